// Round 1
// baseline (2104.700 us; speedup 1.0000x reference)
//
#include <hip/hip_runtime.h>
#include <math.h>

// Problem constants (from reference): z_e [32,256,32,32] fp32, E [4096,256] fp32
// N = 32*32*32 = 32768 queries, K = 4096 codes, C = 256.
// Outputs: z_q [B,C,H,W] (8388608 floats), commitment_loss, utilization.

#define MARGIN 1e-3f   // fp32 screening error bound is ~1.5e-4 worst case; 1e-3 is safe

// ---------------- K1: enorm[k] = sum_c E[k][c]^2 ----------------
__global__ __launch_bounds__(64) void vq_enorm(const float* __restrict__ E,
                                               float* __restrict__ enorm) {
  const int row = blockIdx.x;
  const int lane = threadIdx.x;
  const float4 v = ((const float4*)(E + (size_t)row * 256))[lane];
  float s = v.x * v.x + v.y * v.y + v.z * v.z + v.w * v.w;
#pragma unroll
  for (int off = 32; off > 0; off >>= 1) s += __shfl_down(s, off);
  if (lane == 0) enorm[row] = s;
}

// ---------------- K2: fused distance + top-2 argmin screen ----------------
// block: 256 threads, owns 64 queries x all 4096 codes.
// i = tid&15 -> queries 4i..4i+3 ; j = tid>>4 -> codes (kc + 4j..4j+3)
__global__ __launch_bounds__(256) void vq_screen(
    const float* __restrict__ Z, const float* __restrict__ E,
    const float* __restrict__ enorm, int* __restrict__ idxOut,
    int* __restrict__ flagged, int* __restrict__ flagCount) {
  __shared__ float zt[64 * 256];     // z tile [q][c], XOR-swizzled rows (64 KB)
  __shared__ float ek[2][64 * 32];   // E sub-chunk dbuf [k][c32], swizzled (16 KB)

  const int tid = threadIdx.x;
  const int qbase = blockIdx.x * 64;
  const int b = qbase >> 10;
  const int hwb = qbase & 1023;
  const float* zb = Z + (size_t)b * 262144 + hwb;

  // ---- stage z tile: transpose [c-strided global] -> zt[q][c ^ swz(q)] ----
  {
    const int q = tid & 63;
    const int cb = (tid >> 6) * 64;
    const int sw = ((q >> 2) & 7) << 2;
#pragma unroll 8
    for (int it = 0; it < 64; ++it) {
      const int c = cb + it;
      zt[q * 256 + (c ^ sw)] = zb[(size_t)c * 1024 + q];
    }
  }

  const int i = tid & 15;
  const int j = tid >> 4;
  const int zsw = (i & 7) << 2;   // swizzle for rows 4i+r  ((q>>2)&7 == i&7)
  const int esw = (j & 7) << 2;   // swizzle for rows 4j+s  ((k>>2)&7 == j&7)

  // staging role: thread stages E row sk, 8 floats at col sc8
  const int sk = tid >> 2;
  const int sc8 = (tid & 3) * 8;
  const int ssw = ((sk >> 2) & 7) << 2;
  const size_t sEoff = (size_t)sk * 256 + sc8;
  const int sidx0 = sk * 32 + (sc8 ^ ssw);
  const int sidx1 = sk * 32 + ((sc8 + 4) ^ ssw);

  float m1[4], m2[4];
  int x1[4];
#pragma unroll
  for (int r = 0; r < 4; ++r) { m1[r] = INFINITY; m2[r] = INFINITY; x1[r] = 0; }

  __syncthreads();

  for (int kc = 0; kc < 4096; kc += 64) {
    // prologue: stage sub-chunk 0 into ek[0]
    {
      const float* er = E + (size_t)kc * 256 + sEoff;
      const float4 a = *(const float4*)er;
      const float4 b4 = *(const float4*)(er + 4);
      *(float4*)&ek[0][sidx0] = a;
      *(float4*)&ek[0][sidx1] = b4;
    }
    float acc[4][4];
#pragma unroll
    for (int r = 0; r < 4; ++r)
#pragma unroll
      for (int s = 0; s < 4; ++s) acc[r][s] = 0.f;
    __syncthreads();

#pragma unroll 1
    for (int sc = 0; sc < 8; ++sc) {
      // T14 split: issue next sub-chunk loads early, LDS-write late
      float4 pa, pb;
      if (sc < 7) {
        const float* er = E + (size_t)kc * 256 + (sc + 1) * 32 + sEoff;
        pa = *(const float4*)er;
        pb = *(const float4*)(er + 4);
      }
      const float* eb = ek[sc & 1];
      const int cg0 = sc * 32;
#pragma unroll
      for (int cq = 0; cq < 8; ++cq) {
        const int zo = cg0 + ((cq * 4) ^ zsw);
        const int eo = (cq * 4) ^ esw;
        float4 zq[4], eq[4];
#pragma unroll
        for (int r = 0; r < 4; ++r)
          zq[r] = *(const float4*)&zt[(4 * i + r) * 256 + zo];
#pragma unroll
        for (int s = 0; s < 4; ++s)
          eq[s] = *(const float4*)&eb[(4 * j + s) * 32 + eo];
#pragma unroll
        for (int r = 0; r < 4; ++r)
#pragma unroll
          for (int s = 0; s < 4; ++s) {
            acc[r][s] = fmaf(zq[r].x, eq[s].x, acc[r][s]);
            acc[r][s] = fmaf(zq[r].y, eq[s].y, acc[r][s]);
            acc[r][s] = fmaf(zq[r].z, eq[s].z, acc[r][s]);
            acc[r][s] = fmaf(zq[r].w, eq[s].w, acc[r][s]);
          }
      }
      if (sc < 7) {
        const int nbuf = (sc + 1) & 1;
        *(float4*)&ek[nbuf][sidx0] = pa;
        *(float4*)&ek[nbuf][sidx1] = pb;
      }
      __syncthreads();
    }

    // epilogue: d = enorm[k] - 2*dot ; running top-2 per query
#pragma unroll
    for (int s = 0; s < 4; ++s) {
      const int code = kc + 4 * j + s;
      const float en = enorm[code];
#pragma unroll
      for (int r = 0; r < 4; ++r) {
        const float d = fmaf(-2.f, acc[r][s], en);
        if (d < m1[r]) { m2[r] = m1[r]; m1[r] = d; x1[r] = code; }
        else if (d < m2[r]) { m2[r] = d; }
      }
    }
  }

  // ---- cross-thread (over j) top-2 merge via LDS (reuse zt) ----
  __syncthreads();
  float* RA = zt;                  // [64][16] m1
  float* RB = zt + 1024;           // [64][16] m2
  int* RC = (int*)(zt + 2048);     // [64][16] x1
#pragma unroll
  for (int r = 0; r < 4; ++r) {
    RA[(4 * i + r) * 16 + j] = m1[r];
    RB[(4 * i + r) * 16 + j] = m2[r];
    RC[(4 * i + r) * 16 + j] = x1[r];
  }
  __syncthreads();
  if (tid < 64) {
    float cm1 = INFINITY, cm2 = INFINITY;
    int cx = -1;
    for (int jj = 0; jj < 16; ++jj) {
      const float a1 = RA[tid * 16 + jj];
      const float a2 = RB[tid * 16 + jj];
      const int ax = RC[tid * 16 + jj];
      // (value, index)-lexicographic merge keeps reference first-index tie-break
      if (a1 < cm1 || (a1 == cm1 && ax < cx)) {
        cm2 = fminf(cm1, a2);
        cm1 = a1;
        cx = ax;
      } else {
        cm2 = fminf(cm2, a1);   // a2 >= a1, can't be second
      }
    }
    idxOut[qbase + tid] = cx;
    if (cm2 - cm1 < MARGIN) {
      const int p = atomicAdd(flagCount, 1);
      flagged[p] = qbase + tid;
    }
  }
}

// ---------------- K3: exact fp64 re-argmin for flagged queries ----------------
__global__ __launch_bounds__(256) void vq_refine(
    const float* __restrict__ Z, const float* __restrict__ E,
    const int* __restrict__ flagged, const int* __restrict__ flagCount,
    int* __restrict__ idxOut) {
  __shared__ float zs[256];
  __shared__ double rv[256];
  __shared__ int ri[256];
  const int cnt = *flagCount;
  for (int e = blockIdx.x; e < cnt; e += gridDim.x) {
    const int n = flagged[e];
    const int b = n >> 10, hw = n & 1023;
    __syncthreads();
    zs[threadIdx.x] = Z[(size_t)b * 262144 + (size_t)threadIdx.x * 1024 + hw];
    __syncthreads();
    double bv = 1e300;
    int bi = 0;
    for (int k = threadIdx.x; k < 4096; k += 256) {
      const float* er = E + (size_t)k * 256;
      double d0 = 0, d1 = 0, d2 = 0, d3 = 0;
      for (int c = 0; c < 256; c += 4) {
        const double f0 = (double)zs[c + 0] - (double)er[c + 0];
        const double f1 = (double)zs[c + 1] - (double)er[c + 1];
        const double f2 = (double)zs[c + 2] - (double)er[c + 2];
        const double f3 = (double)zs[c + 3] - (double)er[c + 3];
        d0 = fma(f0, f0, d0);
        d1 = fma(f1, f1, d1);
        d2 = fma(f2, f2, d2);
        d3 = fma(f3, f3, d3);
      }
      const double d = (d0 + d1) + (d2 + d3);
      if (d < bv) { bv = d; bi = k; }  // ascending k per thread keeps first index
    }
    rv[threadIdx.x] = bv;
    ri[threadIdx.x] = bi;
    __syncthreads();
    if (threadIdx.x == 0) {
      double cv = rv[0];
      int ci = ri[0];
      for (int t = 1; t < 256; ++t)
        if (rv[t] < cv || (rv[t] == cv && ri[t] < ci)) { cv = rv[t]; ci = ri[t]; }
      idxOut[n] = ci;
    }
  }
}

// ---------------- K4: gather z_q (transposed out) + fused loss partials ----------------
__global__ __launch_bounds__(256) void vq_out(
    const float* __restrict__ Z, const float* __restrict__ E,
    const int* __restrict__ idx, float* __restrict__ out,
    double* __restrict__ lossSum) {
  const int t = blockIdx.x * 256 + threadIdx.x;
  const int flat = t * 4;                 // out/z_e flat index [b,c,hw]
  const int rem = flat & 262143;
  const int c = rem >> 10;
  const int n = ((flat >> 18) << 10) | (rem & 1023);
  const int4 id4 = *(const int4*)(idx + n);
  const float4 z4 = *(const float4*)(Z + flat);
  float4 o;
  o.x = E[(size_t)id4.x * 256 + c];
  o.y = E[(size_t)id4.y * 256 + c];
  o.z = E[(size_t)id4.z * 256 + c];
  o.w = E[(size_t)id4.w * 256 + c];
  *(float4*)(out + flat) = o;
  const float dx = o.x - z4.x, dy = o.y - z4.y, dz = o.z - z4.z, dw = o.w - z4.w;
  float ls = dx * dx + dy * dy + dz * dz + dw * dw;
#pragma unroll
  for (int off = 32; off > 0; off >>= 1) ls += __shfl_down(ls, off);
  __shared__ float red[4];
  if ((threadIdx.x & 63) == 0) red[threadIdx.x >> 6] = ls;
  __syncthreads();
  if (threadIdx.x == 0)
    atomicAdd(lossSum, (double)((red[0] + red[1]) + (red[2] + red[3])));
}

// ---------------- K4b: mark used codes ----------------
__global__ __launch_bounds__(256) void vq_used(const int* __restrict__ idx,
                                               int* __restrict__ used) {
  const int n = blockIdx.x * 256 + threadIdx.x;
  atomicAdd(&used[idx[n]], 1);
}

// ---------------- K5: finalize scalars ----------------
__global__ __launch_bounds__(256) void vq_final(const int* __restrict__ used,
                                                const double* __restrict__ lossSum,
                                                float* __restrict__ out) {
  __shared__ int cnt[256];
  int c = 0;
  for (int k = threadIdx.x; k < 4096; k += 256) c += (used[k] > 0);
  cnt[threadIdx.x] = c;
  __syncthreads();
  if (threadIdx.x == 0) {
    int tot = 0;
    for (int t = 0; t < 256; ++t) tot += cnt[t];
    out[8388608] = (float)(*lossSum * 0.25 / 8388608.0);
    out[8388609] = (float)tot / 4096.0f;
  }
}

extern "C" void kernel_launch(void* const* d_in, const int* in_sizes, int n_in,
                              void* d_out, int out_size, void* d_ws, size_t ws_size,
                              hipStream_t stream) {
  const float* Z = (const float*)d_in[0];   // z_e [32,256,32,32]
  const float* E = (const float*)d_in[1];   // embed [4096,256]
  float* out = (float*)d_out;               // 8388608 + 2 floats
  char* w = (char*)d_ws;

  int* idx = (int*)w;                        // 131072 B
  int* flagged = (int*)(w + 131072);         // 131072 B
  float* enorm = (float*)(w + 262144);       // 16384 B
  int* used = (int*)(w + 278528);            // 16384 B  [zeroed]
  double* lossSum = (double*)(w + 294912);   // 8 B      [zeroed]
  int* flagCount = (int*)(w + 294920);       // 4 B      [zeroed]

  hipMemsetAsync(w + 278528, 0, 16384 + 16, stream);
  vq_enorm<<<4096, 64, 0, stream>>>(E, enorm);
  vq_screen<<<512, 256, 0, stream>>>(Z, E, enorm, idx, flagged, flagCount);
  vq_refine<<<128, 256, 0, stream>>>(Z, E, flagged, flagCount, idx);
  vq_out<<<8192, 256, 0, stream>>>(Z, E, idx, out, lossSum);
  vq_used<<<128, 256, 0, stream>>>(idx, used);
  vq_final<<<1, 256, 0, stream>>>(used, lossSum, out);
}

// Round 2
// 450.550 us; speedup vs baseline: 4.6714x; 4.6714x over previous
//
#include <hip/hip_runtime.h>
#include <math.h>

// VQ-VAE eval forward. z_e [32,256,32,32] fp32, E [4096,256] fp32.
// N = 32768 queries, K = 4096 codes, C = 256.
// Screen = bf16x2-split MFMA GEMM (3 products: zh*eh + zl*eh + zh*el),
// error ~1e-5 << MARGIN; fp64 refine resolves all gaps < MARGIN exactly.

#define MARGIN 1e-3f

using short8 = __attribute__((ext_vector_type(8))) short;
using f32x4  = __attribute__((ext_vector_type(4))) float;

__device__ __forceinline__ unsigned short f2bf(float x) {
  unsigned u = __float_as_uint(x);
  unsigned r = (u + 0x7fffu + ((u >> 16) & 1u)) >> 16;   // RN-even
  return (unsigned short)r;
}

__device__ __forceinline__ void gload_lds16(const void* g, void* l) {
  __builtin_amdgcn_global_load_lds(
      (const __attribute__((address_space(1))) unsigned int*)g,
      (__attribute__((address_space(3))) unsigned int*)l, 16, 0, 0);
}

// ---------------- K1: enorm[k] = sum_c E[k][c]^2 ----------------
__global__ __launch_bounds__(64) void vq_enorm(const float* __restrict__ E,
                                               float* __restrict__ enorm) {
  const int row = blockIdx.x;
  const int lane = threadIdx.x;
  const float4 v = ((const float4*)(E + (size_t)row * 256))[lane];
  float s = v.x * v.x + v.y * v.y + v.z * v.z + v.w * v.w;
#pragma unroll
  for (int off = 32; off > 0; off >>= 1) s += __shfl_down(s, off);
  if (lane == 0) enorm[row] = s;
}

// ---------------- K2: E -> bf16 hi/lo packed in swizzled LDS-image layout ----------------
// Epk buffer: 128 sub-buffers (chunk_g 0..31 x slice 0..3), each 2048 granules of 16B:
//   hi granules [0,1024): granule = c*8 + (j ^ (c&7)),  c = code&127, j = k-octet within slice
//   lo granules [1024,2048)
__global__ __launch_bounds__(256) void vq_esplit(const float* __restrict__ E,
                                                 uint4* __restrict__ Epk) {
  const int t = blockIdx.x * 256 + threadIdx.x;   // 131072 = 4096 codes x 32 octets
  const int code = t >> 5, jj = t & 31;
  const int slice = jj >> 3, j = jj & 7;
  const int cg = code >> 7, c = code & 127;
  const float* src = E + (size_t)code * 256 + jj * 8;
  unsigned short hs[8], ls[8];
#pragma unroll
  for (int e = 0; e < 8; ++e) {
    const float z = src[e];
    const unsigned short h = f2bf(z);
    const float r = z - __uint_as_float((unsigned)h << 16);   // exact (Sterbenz)
    hs[e] = h;
    ls[e] = f2bf(r);
  }
  const size_t g = (size_t)((cg * 4 + slice) * 2048) + c * 8 + (j ^ (c & 7));
  uint4 hv, lv;
  hv.x = (unsigned)hs[0] | ((unsigned)hs[1] << 16);
  hv.y = (unsigned)hs[2] | ((unsigned)hs[3] << 16);
  hv.z = (unsigned)hs[4] | ((unsigned)hs[5] << 16);
  hv.w = (unsigned)hs[6] | ((unsigned)hs[7] << 16);
  lv.x = (unsigned)ls[0] | ((unsigned)ls[1] << 16);
  lv.y = (unsigned)ls[2] | ((unsigned)ls[3] << 16);
  lv.z = (unsigned)ls[4] | ((unsigned)ls[5] << 16);
  lv.w = (unsigned)ls[6] | ((unsigned)ls[7] << 16);
  Epk[g] = hv;
  Epk[g + 1024] = lv;
}

// ---------------- K3: MFMA screen ----------------
// grid 512 = 256 query-groups (128 q) x 2 code-halves (2048 codes).
// 8 waves x 16 queries; A (queries) in regs for full K=256; E streamed via LDS.
__global__ __launch_bounds__(512) void vq_screen_mfma(
    const float* __restrict__ Z, const char* __restrict__ Epk,
    const float* __restrict__ enorm, float* __restrict__ pm1,
    float* __restrict__ pm2, int* __restrict__ px) {
  __shared__ char lds[65536];   // 2 x 32KB: [hi 16KB | lo 16KB] of 128 codes x 64 k
  const int tid = threadIdx.x;
  const int w = tid >> 6, l = tid & 63;
  const int qg = blockIdx.x >> 1, half = blockIdx.x & 1;
  const int qbase = qg * 128;
  const int b = qbase >> 10;
  const int hw = (qbase & 1023) + w * 16 + (l & 15);

  // ---- A-frags: zh/zl for 16 queries x K=256, 8 k-steps ----
  const float* Zq = Z + (size_t)b * 262144 + hw;
  short8 ah[8], al[8];
#pragma unroll
  for (int ks = 0; ks < 8; ++ks) {
    const int c0 = ks * 32 + (l >> 4) * 8;
#pragma unroll
    for (int e = 0; e < 8; ++e) {
      const float z = Zq[(size_t)(c0 + e) << 10];
      const unsigned short h = f2bf(z);
      const float r = z - __uint_as_float((unsigned)h << 16);
      ah[ks][e] = (short)h;
      al[ks][e] = (short)f2bf(r);
    }
  }

  // swizzled per-lane LDS read offsets (conflict-free: 8 x 16B slots cover 32 banks)
  const int rowoff = (l & 15) * 128;
  const int lo0 = rowoff + ((((l >> 4)) ^ (l & 7)) << 4);       // k-step 0 of slice
  const int lo1 = rowoff + (((4 + (l >> 4)) ^ (l & 7)) << 4);   // k-step 1 of slice
  const int chb4 = half * 64;                                    // 64 slices per half

  float m1[4], m2[4];
  int x1[4];
#pragma unroll
  for (int r = 0; r < 4; ++r) { m1[r] = INFINITY; m2[r] = INFINITY; x1[r] = 0x7fffffff; }

  auto stage = [&](int sel, int sl2) {
    const char* src = Epk + ((size_t)(chb4 + sl2) << 15) + w * 1024 + l * 16;
    char* dst = lds + sel * 32768 + w * 1024;   // wave-uniform base (HW adds lane*16)
#pragma unroll
    for (int i = 0; i < 4; ++i) gload_lds16(src + i * 8192, dst + i * 8192);
  };

  stage(0, 0);   // prologue

  for (int chunk = 0; chunk < 16; ++chunk) {
    f32x4 acc[8];
#pragma unroll
    for (int t = 0; t < 8; ++t) acc[t] = (f32x4){0.f, 0.f, 0.f, 0.f};

#pragma unroll
    for (int s4 = 0; s4 < 4; ++s4) {
      const int sl = chunk * 4 + s4;
      __syncthreads();                       // drains vmcnt(0): cur buffer ready
      if (sl + 1 < 64) stage((sl + 1) & 1, sl + 1);   // async prefetch next slice
      const char* Lb = lds + (sl & 1) * 32768;
#pragma unroll
      for (int s = 0; s < 2; ++s) {
        const int loff = s ? lo1 : lo0;
        const int ks = s4 * 2 + s;
#pragma unroll
        for (int t = 0; t < 8; ++t) {
          const short8 eh = *(const short8*)(Lb + t * 2048 + loff);
          const short8 el = *(const short8*)(Lb + 16384 + t * 2048 + loff);
          acc[t] = __builtin_amdgcn_mfma_f32_16x16x32_bf16(ah[ks], eh, acc[t], 0, 0, 0);
          acc[t] = __builtin_amdgcn_mfma_f32_16x16x32_bf16(al[ks], eh, acc[t], 0, 0, 0);
          acc[t] = __builtin_amdgcn_mfma_f32_16x16x32_bf16(ah[ks], el, acc[t], 0, 0, 0);
        }
      }
    }

    // epilogue: d = enorm - 2*dot; running per-lane top-2 (4 query-rows x 8 codes)
    const int cb = half * 2048 + chunk * 128;
#pragma unroll
    for (int t = 0; t < 8; ++t) {
      const int code = cb + t * 16 + (l & 15);
      const float en = enorm[code];
#pragma unroll
      for (int r = 0; r < 4; ++r) {
        const float d = fmaf(-2.f, acc[t][r], en);
        const bool better = d < m1[r];
        m2[r] = better ? m1[r] : fminf(m2[r], d);
        x1[r] = better ? code : x1[r];
        m1[r] = better ? d : m1[r];
      }
    }
  }

  // ---- cross-lane top-2 merge over the 16 lanes sharing each row-group ----
#pragma unroll
  for (int mask = 1; mask <= 8; mask <<= 1) {
#pragma unroll
    for (int r = 0; r < 4; ++r) {
      const float o1 = __shfl_xor(m1[r], mask);
      const float o2 = __shfl_xor(m2[r], mask);
      const int ox = __shfl_xor(x1[r], mask);
      if (o1 < m1[r] || (o1 == m1[r] && ox < x1[r])) {
        m2[r] = fminf(m1[r], o2);
        m1[r] = o1;
        x1[r] = ox;
      } else {
        m2[r] = fminf(m2[r], o1);
      }
    }
  }
  if ((l & 15) == 0) {
    const int n = qbase + w * 16 + (l >> 4) * 4;
    const int o = half * 32768 + n;
#pragma unroll
    for (int r = 0; r < 4; ++r) {
      pm1[o + r] = m1[r];
      pm2[o + r] = m2[r];
      px[o + r] = x1[r];
    }
  }
}

// ---------------- K4: merge the two code-half partials ----------------
__global__ __launch_bounds__(256) void vq_merge(
    const float* __restrict__ pm1, const float* __restrict__ pm2,
    const int* __restrict__ px, int* __restrict__ idxOut,
    int* __restrict__ flagged, int* __restrict__ flagCount) {
  const int n = blockIdx.x * 256 + threadIdx.x;
  const float a1 = pm1[n], a2 = pm2[n];
  const int ax = px[n];
  const float b1 = pm1[32768 + n], b2 = pm2[32768 + n];
  const int bx = px[32768 + n];
  float m1, m2;
  int x;
  if (b1 < a1) { m1 = b1; x = bx; m2 = fminf(a1, b2); }
  else { m1 = a1; x = ax; m2 = fminf(a2, b1); }   // tie -> half A (lower index)
  idxOut[n] = x;
  if (m2 - m1 < MARGIN) {
    const int p = atomicAdd(flagCount, 1);
    flagged[p] = n;
  }
}

// ---------------- K5: exact fp64 re-argmin for flagged queries ----------------
__global__ __launch_bounds__(256) void vq_refine(
    const float* __restrict__ Z, const float* __restrict__ E,
    const int* __restrict__ flagged, const int* __restrict__ flagCount,
    int* __restrict__ idxOut) {
  __shared__ float zs[256];
  __shared__ double rv[256];
  __shared__ int ri[256];
  const int cnt = *flagCount;
  for (int e = blockIdx.x; e < cnt; e += gridDim.x) {
    const int n = flagged[e];
    const int b = n >> 10, hw = n & 1023;
    __syncthreads();
    zs[threadIdx.x] = Z[(size_t)b * 262144 + (size_t)threadIdx.x * 1024 + hw];
    __syncthreads();
    double bv = 1e300;
    int bi = 0;
    for (int k = threadIdx.x; k < 4096; k += 256) {
      const float* er = E + (size_t)k * 256;
      double d0 = 0, d1 = 0, d2 = 0, d3 = 0;
      for (int c = 0; c < 256; c += 4) {
        const double f0 = (double)zs[c + 0] - (double)er[c + 0];
        const double f1 = (double)zs[c + 1] - (double)er[c + 1];
        const double f2 = (double)zs[c + 2] - (double)er[c + 2];
        const double f3 = (double)zs[c + 3] - (double)er[c + 3];
        d0 = fma(f0, f0, d0);
        d1 = fma(f1, f1, d1);
        d2 = fma(f2, f2, d2);
        d3 = fma(f3, f3, d3);
      }
      const double d = (d0 + d1) + (d2 + d3);
      if (d < bv) { bv = d; bi = k; }
    }
    rv[threadIdx.x] = bv;
    ri[threadIdx.x] = bi;
    __syncthreads();
    if (threadIdx.x == 0) {
      double cv = rv[0];
      int ci = ri[0];
      for (int t = 1; t < 256; ++t)
        if (rv[t] < cv || (rv[t] == cv && ri[t] < ci)) { cv = rv[t]; ci = ri[t]; }
      idxOut[n] = ci;
    }
  }
}

// ---------------- K6: gather z_q (transposed out) + fused loss partials ----------------
__global__ __launch_bounds__(256) void vq_out(
    const float* __restrict__ Z, const float* __restrict__ E,
    const int* __restrict__ idx, float* __restrict__ out,
    double* __restrict__ lossSum) {
  const int t = blockIdx.x * 256 + threadIdx.x;
  const int flat = t * 4;
  const int rem = flat & 262143;
  const int c = rem >> 10;
  const int n = ((flat >> 18) << 10) | (rem & 1023);
  const int4 id4 = *(const int4*)(idx + n);
  const float4 z4 = *(const float4*)(Z + flat);
  float4 o;
  o.x = E[(size_t)id4.x * 256 + c];
  o.y = E[(size_t)id4.y * 256 + c];
  o.z = E[(size_t)id4.z * 256 + c];
  o.w = E[(size_t)id4.w * 256 + c];
  *(float4*)(out + flat) = o;
  const float dx = o.x - z4.x, dy = o.y - z4.y, dz = o.z - z4.z, dw = o.w - z4.w;
  float ls = dx * dx + dy * dy + dz * dz + dw * dw;
#pragma unroll
  for (int off = 32; off > 0; off >>= 1) ls += __shfl_down(ls, off);
  __shared__ float red[4];
  if ((threadIdx.x & 63) == 0) red[threadIdx.x >> 6] = ls;
  __syncthreads();
  if (threadIdx.x == 0)
    atomicAdd(lossSum, (double)((red[0] + red[1]) + (red[2] + red[3])));
}

// ---------------- K7: mark used codes ----------------
__global__ __launch_bounds__(256) void vq_used(const int* __restrict__ idx,
                                               int* __restrict__ used) {
  const int n = blockIdx.x * 256 + threadIdx.x;
  atomicAdd(&used[idx[n]], 1);
}

// ---------------- K8: finalize scalars ----------------
__global__ __launch_bounds__(256) void vq_final(const int* __restrict__ used,
                                                const double* __restrict__ lossSum,
                                                float* __restrict__ out) {
  __shared__ int cnt[256];
  int c = 0;
  for (int k = threadIdx.x; k < 4096; k += 256) c += (used[k] > 0);
  cnt[threadIdx.x] = c;
  __syncthreads();
  if (threadIdx.x == 0) {
    int tot = 0;
    for (int t = 0; t < 256; ++t) tot += cnt[t];
    out[8388608] = (float)(*lossSum * 0.25 / 8388608.0);
    out[8388609] = (float)tot / 4096.0f;
  }
}

extern "C" void kernel_launch(void* const* d_in, const int* in_sizes, int n_in,
                              void* d_out, int out_size, void* d_ws, size_t ws_size,
                              hipStream_t stream) {
  const float* Z = (const float*)d_in[0];
  const float* E = (const float*)d_in[1];
  float* out = (float*)d_out;
  char* w = (char*)d_ws;

  int* idx = (int*)w;                        // 131072 B
  int* flagged = (int*)(w + 131072);         // 131072 B
  float* enorm = (float*)(w + 262144);       // 16384 B
  int* used = (int*)(w + 278528);            // 16384 B [zeroed]
  double* lossSum = (double*)(w + 294912);   // 8 B     [zeroed]
  int* flagCount = (int*)(w + 294920);       // 4 B     [zeroed]

  // d_out doubles as scratch; vq_out/vq_final rewrite all of it afterwards.
  char* Epk = (char*)out;                    // 4 MB packed bf16 E (floats [0, 1048576))
  float* pm1 = out + 1048576;                // 2 x 32768
  float* pm2 = out + 1114112;                // 2 x 32768
  int* px = (int*)(out + 1179648);           // 2 x 32768

  hipMemsetAsync(w + 278528, 0, 16384 + 16, stream);
  vq_enorm<<<4096, 64, 0, stream>>>(E, enorm);
  vq_esplit<<<512, 256, 0, stream>>>(E, (uint4*)Epk);
  vq_screen_mfma<<<512, 512, 0, stream>>>(Z, Epk, enorm, pm1, pm2, px);
  vq_merge<<<128, 256, 0, stream>>>(pm1, pm2, px, idx, flagged, flagCount);
  vq_refine<<<128, 256, 0, stream>>>(Z, E, flagged, flagCount, idx);
  vq_out<<<8192, 256, 0, stream>>>(Z, E, idx, out, lossSum);
  vq_used<<<128, 256, 0, stream>>>(idx, used);
  vq_final<<<1, 256, 0, stream>>>(used, lossSum, out);
}

// Round 3
// 370.651 us; speedup vs baseline: 5.6784x; 1.2156x over previous
//
#include <hip/hip_runtime.h>
#include <math.h>

// VQ-VAE eval forward. z_e [32,256,32,32] fp32, E [4096,256] fp32.
// N = 32768 queries, K = 4096 codes, C = 256.
// Screen = bf16x2-split MFMA GEMM (3 products: zh*eh + zl*eh + zh*el),
// error ~1e-5 << MARGIN; fp64 refine resolves all gaps < MARGIN exactly.
// Round 3: 2 query-tiles/wave (halves LDS-read per MFMA -> MFMA-bound),
// row-gather vq_out via LDS transpose, prep fusion.

#define MARGIN 1e-3f

using short8 = __attribute__((ext_vector_type(8))) short;
using f32x4  = __attribute__((ext_vector_type(4))) float;

__device__ __forceinline__ unsigned short f2bf(float x) {
  unsigned u = __float_as_uint(x);
  unsigned r = (u + 0x7fffu + ((u >> 16) & 1u)) >> 16;   // RN-even
  return (unsigned short)r;
}

__device__ __forceinline__ void gload_lds16(const void* g, void* l) {
  __builtin_amdgcn_global_load_lds(
      (const __attribute__((address_space(1))) unsigned int*)g,
      (__attribute__((address_space(3))) unsigned int*)l, 16, 0, 0);
}

// ---------------- K1: fused E split (hi/lo bf16, swizzled image) + enorm ----------------
__global__ __launch_bounds__(256) void vq_prep(const float* __restrict__ E,
                                               uint4* __restrict__ Epk,
                                               float* __restrict__ enorm) {
  const int t = blockIdx.x * 256 + threadIdx.x;   // 131072 = 4096 codes x 32 octets
  const int code = t >> 5, jj = t & 31;
  const int slice = jj >> 3, j = jj & 7;
  const int cg = code >> 7, c = code & 127;
  const float* src = E + (size_t)code * 256 + jj * 8;
  unsigned short hs[8], ls[8];
  float s = 0.f;
#pragma unroll
  for (int e = 0; e < 8; ++e) {
    const float z = src[e];
    s = fmaf(z, z, s);
    const unsigned short h = f2bf(z);
    const float r = z - __uint_as_float((unsigned)h << 16);   // exact (Sterbenz)
    hs[e] = h;
    ls[e] = f2bf(r);
  }
  const size_t g = (size_t)((cg * 4 + slice) * 2048) + c * 8 + (j ^ (c & 7));
  uint4 hv, lv;
  hv.x = (unsigned)hs[0] | ((unsigned)hs[1] << 16);
  hv.y = (unsigned)hs[2] | ((unsigned)hs[3] << 16);
  hv.z = (unsigned)hs[4] | ((unsigned)hs[5] << 16);
  hv.w = (unsigned)hs[6] | ((unsigned)hs[7] << 16);
  lv.x = (unsigned)ls[0] | ((unsigned)ls[1] << 16);
  lv.y = (unsigned)ls[2] | ((unsigned)ls[3] << 16);
  lv.z = (unsigned)ls[4] | ((unsigned)ls[5] << 16);
  lv.w = (unsigned)ls[6] | ((unsigned)ls[7] << 16);
  Epk[g] = hv;
  Epk[g + 1024] = lv;
  // enorm: reduce Sum z^2 across the 32 lanes of this code
#pragma unroll
  for (int off = 1; off < 32; off <<= 1) s += __shfl_xor(s, off);
  if (jj == 0) enorm[code] = s;
}

// ---------------- K2: MFMA screen, 2 query-tiles per wave ----------------
// grid 256 = 128 query-groups (256 q) x 2 code-halves (2048 codes).
// 8 waves x 32 queries (2 x 16); A in regs for full K=256; E streamed via LDS.
__global__ __launch_bounds__(512, 2) void vq_screen(
    const float* __restrict__ Z, const char* __restrict__ Epk,
    const float* __restrict__ enorm, float* __restrict__ pm1,
    float* __restrict__ pm2, int* __restrict__ px) {
  __shared__ char lds[65536];   // 2 x 32KB: [hi 16KB | lo 16KB] of 128 codes x 64 k
  const int tid = threadIdx.x;
  const int w = tid >> 6, l = tid & 63;
  const int qg = blockIdx.x >> 1, half = blockIdx.x & 1;
  const int qbase = qg * 256;
  const int b = qbase >> 10;
  const int hwq = (qbase & 1023) + w * 32 + (l & 15);

  // ---- A-frags: zh/zl for 2 tiles x 16 queries x K=256 ----
  const float* Zq = Z + (size_t)b * 262144 + hwq;
  short8 ah[2][8], al[2][8];
#pragma unroll
  for (int u = 0; u < 2; ++u)
#pragma unroll
    for (int ks = 0; ks < 8; ++ks) {
      const int c0 = ks * 32 + (l >> 4) * 8;
#pragma unroll
      for (int e = 0; e < 8; ++e) {
        const float z = Zq[u * 16 + ((size_t)(c0 + e) << 10)];
        const unsigned short h = f2bf(z);
        const float r = z - __uint_as_float((unsigned)h << 16);
        ah[u][ks][e] = (short)h;
        al[u][ks][e] = (short)f2bf(r);
      }
    }

  // swizzled per-lane LDS read offsets (8 x 16B slots cover 32 banks)
  const int rowoff = (l & 15) * 128;
  const int lo0 = rowoff + (((l >> 4) ^ (l & 7)) << 4);
  const int lo1 = rowoff + ((((l >> 4) + 4) ^ (l & 7)) << 4);
  const int chb4 = half * 64;   // 64 slices per half

  float m1[2][4], m2[2][4];
  int x1[2][4];
#pragma unroll
  for (int u = 0; u < 2; ++u)
#pragma unroll
    for (int r = 0; r < 4; ++r) {
      m1[u][r] = INFINITY; m2[u][r] = INFINITY; x1[u][r] = 0x7fffffff;
    }

  auto stage = [&](int sel, int sl2) {
    const char* src = Epk + ((size_t)(chb4 + sl2) << 15) + w * 1024 + l * 16;
    char* dst = lds + sel * 32768 + w * 1024;   // wave-uniform base (HW adds lane*16)
#pragma unroll
    for (int i = 0; i < 4; ++i) gload_lds16(src + i * 8192, dst + i * 8192);
  };

  stage(0, 0);   // prologue

  for (int chunk = 0; chunk < 16; ++chunk) {
    f32x4 acc[2][8];
#pragma unroll
    for (int u = 0; u < 2; ++u)
#pragma unroll
      for (int t = 0; t < 8; ++t) acc[u][t] = (f32x4){0.f, 0.f, 0.f, 0.f};

#pragma unroll
    for (int s4 = 0; s4 < 4; ++s4) {
      const int sl = chunk * 4 + s4;
      __syncthreads();                                // drains vmcnt: cur buffer ready
      if (sl + 1 < 64) stage((sl + 1) & 1, sl + 1);   // async prefetch next slice
      const char* Lb = lds + (sl & 1) * 32768;
#pragma unroll
      for (int s = 0; s < 2; ++s) {
        const int loff = s ? lo1 : lo0;
        const int ks = s4 * 2 + s;
#pragma unroll
        for (int t = 0; t < 8; ++t) {
          const short8 eh = *(const short8*)(Lb + t * 2048 + loff);
          const short8 el = *(const short8*)(Lb + 16384 + t * 2048 + loff);
          acc[0][t] = __builtin_amdgcn_mfma_f32_16x16x32_bf16(ah[0][ks], eh, acc[0][t], 0, 0, 0);
          acc[1][t] = __builtin_amdgcn_mfma_f32_16x16x32_bf16(ah[1][ks], eh, acc[1][t], 0, 0, 0);
          acc[0][t] = __builtin_amdgcn_mfma_f32_16x16x32_bf16(al[0][ks], eh, acc[0][t], 0, 0, 0);
          acc[1][t] = __builtin_amdgcn_mfma_f32_16x16x32_bf16(al[1][ks], eh, acc[1][t], 0, 0, 0);
          acc[0][t] = __builtin_amdgcn_mfma_f32_16x16x32_bf16(ah[0][ks], el, acc[0][t], 0, 0, 0);
          acc[1][t] = __builtin_amdgcn_mfma_f32_16x16x32_bf16(ah[1][ks], el, acc[1][t], 0, 0, 0);
        }
      }
    }

    // epilogue: d = enorm - 2*dot; running per-lane top-2
    const int cb = half * 2048 + chunk * 128;
#pragma unroll
    for (int t = 0; t < 8; ++t) {
      const int code = cb + t * 16 + (l & 15);
      const float en = enorm[code];
#pragma unroll
      for (int u = 0; u < 2; ++u)
#pragma unroll
        for (int r = 0; r < 4; ++r) {
          const float d = fmaf(-2.f, acc[u][t][r], en);
          const bool better = d < m1[u][r];
          m2[u][r] = better ? m1[u][r] : fminf(m2[u][r], d);
          x1[u][r] = better ? code : x1[u][r];
          m1[u][r] = better ? d : m1[u][r];
        }
    }
  }

  // ---- cross-lane top-2 merge over the 16 lanes sharing each row-group ----
#pragma unroll
  for (int mask = 1; mask <= 8; mask <<= 1) {
#pragma unroll
    for (int u = 0; u < 2; ++u)
#pragma unroll
      for (int r = 0; r < 4; ++r) {
        const float o1 = __shfl_xor(m1[u][r], mask);
        const float o2 = __shfl_xor(m2[u][r], mask);
        const int ox = __shfl_xor(x1[u][r], mask);
        if (o1 < m1[u][r] || (o1 == m1[u][r] && ox < x1[u][r])) {
          m2[u][r] = fminf(m1[u][r], o2);
          m1[u][r] = o1;
          x1[u][r] = ox;
        } else {
          m2[u][r] = fminf(m2[u][r], o1);
        }
      }
  }
  if ((l & 15) == 0) {
#pragma unroll
    for (int u = 0; u < 2; ++u) {
      const int n = qbase + w * 32 + u * 16 + (l >> 4) * 4;
      const int o = half * 32768 + n;
#pragma unroll
      for (int r = 0; r < 4; ++r) {
        pm1[o + r] = m1[u][r];
        pm2[o + r] = m2[u][r];
        px[o + r] = x1[u][r];
      }
    }
  }
}

// ---------------- K3: merge the two code-half partials ----------------
__global__ __launch_bounds__(256) void vq_merge(
    const float* __restrict__ pm1, const float* __restrict__ pm2,
    const int* __restrict__ px, int* __restrict__ idxOut,
    int* __restrict__ flagged, int* __restrict__ flagCount) {
  const int n = blockIdx.x * 256 + threadIdx.x;
  const float a1 = pm1[n], a2 = pm2[n];
  const int ax = px[n];
  const float b1 = pm1[32768 + n], b2 = pm2[32768 + n];
  const int bx = px[32768 + n];
  float m1, m2;
  int x;
  if (b1 < a1) { m1 = b1; x = bx; m2 = fminf(a1, b2); }
  else { m1 = a1; x = ax; m2 = fminf(a2, b1); }   // tie -> half A (lower index)
  idxOut[n] = x;
  if (m2 - m1 < MARGIN) {
    const int p = atomicAdd(flagCount, 1);
    flagged[p] = n;
  }
}

// ---------------- K4: exact fp64 re-argmin for flagged queries ----------------
__global__ __launch_bounds__(256) void vq_refine(
    const float* __restrict__ Z, const float* __restrict__ E,
    const int* __restrict__ flagged, const int* __restrict__ flagCount,
    int* __restrict__ idxOut) {
  __shared__ float zs[256];
  __shared__ double rv[256];
  __shared__ int ri[256];
  const int cnt = *flagCount;
  for (int e = blockIdx.x; e < cnt; e += gridDim.x) {
    const int n = flagged[e];
    const int b = n >> 10, hw = n & 1023;
    __syncthreads();
    zs[threadIdx.x] = Z[(size_t)b * 262144 + (size_t)threadIdx.x * 1024 + hw];
    __syncthreads();
    double bv = 1e300;
    int bi = 0;
    for (int k = threadIdx.x; k < 4096; k += 256) {
      const float* er = E + (size_t)k * 256;
      double d0 = 0, d1 = 0, d2 = 0, d3 = 0;
      for (int c = 0; c < 256; c += 4) {
        const double f0 = (double)zs[c + 0] - (double)er[c + 0];
        const double f1 = (double)zs[c + 1] - (double)er[c + 1];
        const double f2 = (double)zs[c + 2] - (double)er[c + 2];
        const double f3 = (double)zs[c + 3] - (double)er[c + 3];
        d0 = fma(f0, f0, d0);
        d1 = fma(f1, f1, d1);
        d2 = fma(f2, f2, d2);
        d3 = fma(f3, f3, d3);
      }
      const double d = (d0 + d1) + (d2 + d3);
      if (d < bv) { bv = d; bi = k; }  // ascending k keeps first index per thread
    }
    rv[threadIdx.x] = bv;
    ri[threadIdx.x] = bi;
    __syncthreads();
    if (threadIdx.x == 0) {
      double cv = rv[0];
      int ci = ri[0];
      for (int t = 1; t < 256; ++t)
        if (rv[t] < cv || (rv[t] == cv && ri[t] < ci)) { cv = rv[t]; ci = ri[t]; }
      idxOut[n] = ci;
    }
  }
}

// ---------------- K5: row-gather z_q + loss + used marking ----------------
// block = 32 consecutive queries (one b). Stage E rows coalesced into LDS,
// emit transposed [b][c][hw] output in 128B chunks.
__global__ __launch_bounds__(256) void vq_out(
    const float* __restrict__ Z, const float* __restrict__ E,
    const int* __restrict__ idx, float* __restrict__ out,
    double* __restrict__ lossSum, int* __restrict__ used) {
  __shared__ float zt[32][257];   // +1 pad: conflict-free column reads
  __shared__ int ids[32];
  const int tid = threadIdx.x;
  const int qb = blockIdx.x * 32;
  const int b = qb >> 10, hw0 = qb & 1023;
  if (tid < 32) {
    const int id = idx[qb + tid];
    ids[tid] = id;
    used[id] = 1;                 // post-refine -> final codes
  }
  __syncthreads();
  // stage 32 E rows; wave w owns rows w, w+4, ... (1KB coalesced per row)
  const int w = tid >> 6, l = tid & 63;
#pragma unroll
  for (int rr = 0; rr < 8; ++rr) {
    const int q = rr * 4 + w;
    const float4 v = *(const float4*)(E + (size_t)ids[q] * 256 + l * 4);
    zt[q][l * 4 + 0] = v.x;
    zt[q][l * 4 + 1] = v.y;
    zt[q][l * 4 + 2] = v.z;
    zt[q][l * 4 + 3] = v.w;
  }
  __syncthreads();
  // output + loss: thread (hwl, cc) walks 32 c's
  const int hwl = tid & 31, cc = tid >> 5;
  const float* Zb = Z + (size_t)b * 262144 + hw0 + hwl;
  float* Ob = out + (size_t)b * 262144 + hw0 + hwl;
  float ls = 0.f;
#pragma unroll 4
  for (int it = 0; it < 32; ++it) {
    const int c = it * 8 + cc;
    const float o = zt[hwl][c];
    const float z = Zb[(size_t)c << 10];
    Ob[(size_t)c << 10] = o;
    const float d = o - z;
    ls = fmaf(d, d, ls);
  }
#pragma unroll
  for (int off = 32; off > 0; off >>= 1) ls += __shfl_down(ls, off);
  __shared__ float red[4];
  if (l == 0) red[w] = ls;
  __syncthreads();
  if (tid == 0)
    atomicAdd(lossSum, (double)((red[0] + red[1]) + (red[2] + red[3])));
}

// ---------------- K6: finalize scalars ----------------
__global__ __launch_bounds__(256) void vq_final(const int* __restrict__ used,
                                                const double* __restrict__ lossSum,
                                                float* __restrict__ out) {
  __shared__ int cnt[256];
  int c = 0;
  for (int k = threadIdx.x; k < 4096; k += 256) c += (used[k] > 0);
  cnt[threadIdx.x] = c;
  __syncthreads();
  if (threadIdx.x == 0) {
    int tot = 0;
    for (int t = 0; t < 256; ++t) tot += cnt[t];
    out[8388608] = (float)(*lossSum * 0.25 / 8388608.0);
    out[8388609] = (float)tot / 4096.0f;
  }
}

extern "C" void kernel_launch(void* const* d_in, const int* in_sizes, int n_in,
                              void* d_out, int out_size, void* d_ws, size_t ws_size,
                              hipStream_t stream) {
  const float* Z = (const float*)d_in[0];
  const float* E = (const float*)d_in[1];
  float* out = (float*)d_out;
  char* w = (char*)d_ws;

  int* idx = (int*)w;                        // 131072 B
  int* flagged = (int*)(w + 131072);         // 131072 B
  float* enorm = (float*)(w + 262144);       // 16384 B
  int* used = (int*)(w + 278528);            // 16384 B [zeroed]
  double* lossSum = (double*)(w + 294912);   // 8 B     [zeroed]
  int* flagCount = (int*)(w + 294920);       // 4 B     [zeroed]

  // d_out doubles as scratch; all regions consumed before vq_out rewrites out.
  char* Epk = (char*)out;                    // 4 MB packed bf16 E (floats [0, 1048576))
  float* pm1 = out + 1048576;                // 2 x 32768
  float* pm2 = out + 1114112;                // 2 x 32768
  int* px = (int*)(out + 1179648);           // 2 x 32768

  hipMemsetAsync(w + 278528, 0, 16384 + 16, stream);
  vq_prep<<<512, 256, 0, stream>>>(E, (uint4*)Epk, enorm);
  vq_screen<<<256, 512, 0, stream>>>(Z, Epk, enorm, pm1, pm2, px);
  vq_merge<<<128, 256, 0, stream>>>(pm1, pm2, px, idx, flagged, flagCount);
  vq_refine<<<256, 256, 0, stream>>>(Z, E, flagged, flagCount, idx);
  vq_out<<<1024, 256, 0, stream>>>(Z, E, idx, out, lossSum, used);
  vq_final<<<1, 256, 0, stream>>>(used, lossSum, out);
}

// Round 4
// 369.286 us; speedup vs baseline: 5.6994x; 1.0037x over previous
//
#include <hip/hip_runtime.h>
#include <math.h>

// VQ-VAE eval forward. z_e [32,256,32,32] fp32, E [4096,256] fp32.
// N = 32768 queries, K = 4096 codes, C = 256.
// Screen = bf16x2-split MFMA GEMM (3 products: zh*eh + zl*eh + zh*el),
// error ~1e-5 << MARGIN; fp64 refine resolves all gaps < MARGIN exactly.
// Round 4: 4-wave blocks x 512 -> 2 independent blocks/CU (barrier overlap),
// T5 setprio around MFMA cluster. Numerics/layouts unchanged from round 3.

#define MARGIN 1e-3f

using short8 = __attribute__((ext_vector_type(8))) short;
using f32x4  = __attribute__((ext_vector_type(4))) float;

__device__ __forceinline__ unsigned short f2bf(float x) {
  unsigned u = __float_as_uint(x);
  unsigned r = (u + 0x7fffu + ((u >> 16) & 1u)) >> 16;   // RN-even
  return (unsigned short)r;
}

__device__ __forceinline__ void gload_lds16(const void* g, void* l) {
  __builtin_amdgcn_global_load_lds(
      (const __attribute__((address_space(1))) unsigned int*)g,
      (__attribute__((address_space(3))) unsigned int*)l, 16, 0, 0);
}

// ---------------- K1: fused E split (hi/lo bf16, swizzled image) + enorm ----------------
__global__ __launch_bounds__(256) void vq_prep(const float* __restrict__ E,
                                               uint4* __restrict__ Epk,
                                               float* __restrict__ enorm) {
  const int t = blockIdx.x * 256 + threadIdx.x;   // 131072 = 4096 codes x 32 octets
  const int code = t >> 5, jj = t & 31;
  const int slice = jj >> 3, j = jj & 7;
  const int cg = code >> 7, c = code & 127;
  const float* src = E + (size_t)code * 256 + jj * 8;
  unsigned short hs[8], ls[8];
  float s = 0.f;
#pragma unroll
  for (int e = 0; e < 8; ++e) {
    const float z = src[e];
    s = fmaf(z, z, s);
    const unsigned short h = f2bf(z);
    const float r = z - __uint_as_float((unsigned)h << 16);   // exact (Sterbenz)
    hs[e] = h;
    ls[e] = f2bf(r);
  }
  const size_t g = (size_t)((cg * 4 + slice) * 2048) + c * 8 + (j ^ (c & 7));
  uint4 hv, lv;
  hv.x = (unsigned)hs[0] | ((unsigned)hs[1] << 16);
  hv.y = (unsigned)hs[2] | ((unsigned)hs[3] << 16);
  hv.z = (unsigned)hs[4] | ((unsigned)hs[5] << 16);
  hv.w = (unsigned)hs[6] | ((unsigned)hs[7] << 16);
  lv.x = (unsigned)ls[0] | ((unsigned)ls[1] << 16);
  lv.y = (unsigned)ls[2] | ((unsigned)ls[3] << 16);
  lv.z = (unsigned)ls[4] | ((unsigned)ls[5] << 16);
  lv.w = (unsigned)ls[6] | ((unsigned)ls[7] << 16);
  Epk[g] = hv;
  Epk[g + 1024] = lv;
#pragma unroll
  for (int off = 1; off < 32; off <<= 1) s += __shfl_xor(s, off);
  if (jj == 0) enorm[code] = s;
}

// ---------------- K2: MFMA screen ----------------
// grid 512 = 256 query-groups (128 q) x 2 code-halves (2048 codes).
// 4 waves x 32 queries (2 tiles of 16); A in regs for full K=256; E via LDS.
// 2 independent blocks per CU (64KB LDS each, <=256 regs) -> barrier overlap.
__global__ __launch_bounds__(256, 2) void vq_screen(
    const float* __restrict__ Z, const char* __restrict__ Epk,
    const float* __restrict__ enorm, float* __restrict__ pm1,
    float* __restrict__ pm2, int* __restrict__ px) {
  __shared__ char lds[65536];   // 2 x 32KB: [hi 16KB | lo 16KB] of 128 codes x 64 k
  const int tid = threadIdx.x;
  const int w = tid >> 6, l = tid & 63;
  const int qg = blockIdx.x >> 1, half = blockIdx.x & 1;
  const int qbase = qg * 128;
  const int b = qbase >> 10;
  const int hwq = (qbase & 1023) + w * 32 + (l & 15);

  // ---- A-frags: zh/zl for 2 tiles x 16 queries x K=256 ----
  const float* Zq = Z + (size_t)b * 262144 + hwq;
  short8 ah[2][8], al[2][8];
#pragma unroll
  for (int u = 0; u < 2; ++u)
#pragma unroll
    for (int ks = 0; ks < 8; ++ks) {
      const int c0 = ks * 32 + (l >> 4) * 8;
#pragma unroll
      for (int e = 0; e < 8; ++e) {
        const float z = Zq[u * 16 + ((size_t)(c0 + e) << 10)];
        const unsigned short h = f2bf(z);
        const float r = z - __uint_as_float((unsigned)h << 16);
        ah[u][ks][e] = (short)h;
        al[u][ks][e] = (short)f2bf(r);
      }
    }

  // swizzled per-lane LDS read offsets (8 x 16B slots cover 32 banks)
  const int rowoff = (l & 15) * 128;
  const int lo0 = rowoff + (((l >> 4) ^ (l & 7)) << 4);
  const int lo1 = rowoff + ((((l >> 4) + 4) ^ (l & 7)) << 4);
  const int chb = half * 64;   // 64 slices per half

  float m1[2][4], m2[2][4];
  int x1[2][4];
#pragma unroll
  for (int u = 0; u < 2; ++u)
#pragma unroll
    for (int r = 0; r < 4; ++r) {
      m1[u][r] = INFINITY; m2[u][r] = INFINITY; x1[u][r] = 0x7fffffff;
    }

  // stage one 32KB slice: wave w stages [w*8KB, w*8KB+8KB), linear dst (rule 21)
  auto stage = [&](int sel, int sl2) {
    const char* src = Epk + ((size_t)(chb + sl2) << 15) + w * 8192 + l * 16;
    char* dst = lds + sel * 32768 + w * 8192;   // wave-uniform base (HW adds lane*16)
#pragma unroll
    for (int i = 0; i < 8; ++i) gload_lds16(src + i * 1024, dst + i * 1024);
  };

  stage(0, 0);   // prologue

  for (int chunk = 0; chunk < 16; ++chunk) {
    f32x4 acc[2][8];
#pragma unroll
    for (int u = 0; u < 2; ++u)
#pragma unroll
      for (int t = 0; t < 8; ++t) acc[u][t] = (f32x4){0.f, 0.f, 0.f, 0.f};

#pragma unroll
    for (int s4 = 0; s4 < 4; ++s4) {
      const int sl = chunk * 4 + s4;
      __syncthreads();                                // cur buffer ready
      if (sl + 1 < 64) stage((sl + 1) & 1, sl + 1);   // async prefetch next slice
      const char* Lb = lds + (sl & 1) * 32768;
      __builtin_amdgcn_s_setprio(1);
#pragma unroll
      for (int s = 0; s < 2; ++s) {
        const int loff = s ? lo1 : lo0;
        const int ks = s4 * 2 + s;
#pragma unroll
        for (int t = 0; t < 8; ++t) {
          const short8 eh = *(const short8*)(Lb + t * 2048 + loff);
          const short8 el = *(const short8*)(Lb + 16384 + t * 2048 + loff);
          acc[0][t] = __builtin_amdgcn_mfma_f32_16x16x32_bf16(ah[0][ks], eh, acc[0][t], 0, 0, 0);
          acc[1][t] = __builtin_amdgcn_mfma_f32_16x16x32_bf16(ah[1][ks], eh, acc[1][t], 0, 0, 0);
          acc[0][t] = __builtin_amdgcn_mfma_f32_16x16x32_bf16(al[0][ks], eh, acc[0][t], 0, 0, 0);
          acc[1][t] = __builtin_amdgcn_mfma_f32_16x16x32_bf16(al[1][ks], eh, acc[1][t], 0, 0, 0);
          acc[0][t] = __builtin_amdgcn_mfma_f32_16x16x32_bf16(ah[0][ks], el, acc[0][t], 0, 0, 0);
          acc[1][t] = __builtin_amdgcn_mfma_f32_16x16x32_bf16(ah[1][ks], el, acc[1][t], 0, 0, 0);
        }
      }
      __builtin_amdgcn_s_setprio(0);
    }

    // epilogue: d = enorm - 2*dot; running per-lane top-2
    const int cb = half * 2048 + chunk * 128;
#pragma unroll
    for (int t = 0; t < 8; ++t) {
      const int code = cb + t * 16 + (l & 15);
      const float en = enorm[code];
#pragma unroll
      for (int u = 0; u < 2; ++u)
#pragma unroll
        for (int r = 0; r < 4; ++r) {
          const float d = fmaf(-2.f, acc[u][t][r], en);
          const bool better = d < m1[u][r];
          m2[u][r] = better ? m1[u][r] : fminf(m2[u][r], d);
          x1[u][r] = better ? code : x1[u][r];
          m1[u][r] = better ? d : m1[u][r];
        }
    }
  }

  // ---- cross-lane top-2 merge over the 16 lanes sharing each row-group ----
#pragma unroll
  for (int mask = 1; mask <= 8; mask <<= 1) {
#pragma unroll
    for (int u = 0; u < 2; ++u)
#pragma unroll
      for (int r = 0; r < 4; ++r) {
        const float o1 = __shfl_xor(m1[u][r], mask);
        const float o2 = __shfl_xor(m2[u][r], mask);
        const int ox = __shfl_xor(x1[u][r], mask);
        if (o1 < m1[u][r] || (o1 == m1[u][r] && ox < x1[u][r])) {
          m2[u][r] = fminf(m1[u][r], o2);
          m1[u][r] = o1;
          x1[u][r] = ox;
        } else {
          m2[u][r] = fminf(m2[u][r], o1);
        }
      }
  }
  if ((l & 15) == 0) {
#pragma unroll
    for (int u = 0; u < 2; ++u) {
      const int n = qbase + w * 32 + u * 16 + (l >> 4) * 4;
      const int o = half * 32768 + n;
#pragma unroll
      for (int r = 0; r < 4; ++r) {
        pm1[o + r] = m1[u][r];
        pm2[o + r] = m2[u][r];
        px[o + r] = x1[u][r];
      }
    }
  }
}

// ---------------- K3: merge the two code-half partials ----------------
__global__ __launch_bounds__(256) void vq_merge(
    const float* __restrict__ pm1, const float* __restrict__ pm2,
    const int* __restrict__ px, int* __restrict__ idxOut,
    int* __restrict__ flagged, int* __restrict__ flagCount) {
  const int n = blockIdx.x * 256 + threadIdx.x;
  const float a1 = pm1[n], a2 = pm2[n];
  const int ax = px[n];
  const float b1 = pm1[32768 + n], b2 = pm2[32768 + n];
  const int bx = px[32768 + n];
  float m1, m2;
  int x;
  if (b1 < a1) { m1 = b1; x = bx; m2 = fminf(a1, b2); }
  else { m1 = a1; x = ax; m2 = fminf(a2, b1); }   // tie -> half A (lower index)
  idxOut[n] = x;
  if (m2 - m1 < MARGIN) {
    const int p = atomicAdd(flagCount, 1);
    flagged[p] = n;
  }
}

// ---------------- K4: exact fp64 re-argmin for flagged queries ----------------
__global__ __launch_bounds__(256) void vq_refine(
    const float* __restrict__ Z, const float* __restrict__ E,
    const int* __restrict__ flagged, const int* __restrict__ flagCount,
    int* __restrict__ idxOut) {
  __shared__ float zs[256];
  __shared__ double rv[256];
  __shared__ int ri[256];
  const int cnt = *flagCount;
  for (int e = blockIdx.x; e < cnt; e += gridDim.x) {
    const int n = flagged[e];
    const int b = n >> 10, hw = n & 1023;
    __syncthreads();
    zs[threadIdx.x] = Z[(size_t)b * 262144 + (size_t)threadIdx.x * 1024 + hw];
    __syncthreads();
    double bv = 1e300;
    int bi = 0;
    for (int k = threadIdx.x; k < 4096; k += 256) {
      const float* er = E + (size_t)k * 256;
      double d0 = 0, d1 = 0, d2 = 0, d3 = 0;
      for (int c = 0; c < 256; c += 4) {
        const double f0 = (double)zs[c + 0] - (double)er[c + 0];
        const double f1 = (double)zs[c + 1] - (double)er[c + 1];
        const double f2 = (double)zs[c + 2] - (double)er[c + 2];
        const double f3 = (double)zs[c + 3] - (double)er[c + 3];
        d0 = fma(f0, f0, d0);
        d1 = fma(f1, f1, d1);
        d2 = fma(f2, f2, d2);
        d3 = fma(f3, f3, d3);
      }
      const double d = (d0 + d1) + (d2 + d3);
      if (d < bv) { bv = d; bi = k; }  // ascending k keeps first index per thread
    }
    rv[threadIdx.x] = bv;
    ri[threadIdx.x] = bi;
    __syncthreads();
    if (threadIdx.x == 0) {
      double cv = rv[0];
      int ci = ri[0];
      for (int t = 1; t < 256; ++t)
        if (rv[t] < cv || (rv[t] == cv && ri[t] < ci)) { cv = rv[t]; ci = ri[t]; }
      idxOut[n] = ci;
    }
  }
}

// ---------------- K5: row-gather z_q + loss + used marking ----------------
__global__ __launch_bounds__(256) void vq_out(
    const float* __restrict__ Z, const float* __restrict__ E,
    const int* __restrict__ idx, float* __restrict__ out,
    double* __restrict__ lossSum, int* __restrict__ used) {
  __shared__ float zt[32][257];   // +1 pad: conflict-free column reads
  __shared__ int ids[32];
  const int tid = threadIdx.x;
  const int qb = blockIdx.x * 32;
  const int b = qb >> 10, hw0 = qb & 1023;
  if (tid < 32) {
    const int id = idx[qb + tid];
    ids[tid] = id;
    used[id] = 1;                 // post-refine -> final codes
  }
  __syncthreads();
  const int w = tid >> 6, l = tid & 63;
#pragma unroll
  for (int rr = 0; rr < 8; ++rr) {
    const int q = rr * 4 + w;
    const float4 v = *(const float4*)(E + (size_t)ids[q] * 256 + l * 4);
    zt[q][l * 4 + 0] = v.x;
    zt[q][l * 4 + 1] = v.y;
    zt[q][l * 4 + 2] = v.z;
    zt[q][l * 4 + 3] = v.w;
  }
  __syncthreads();
  const int hwl = tid & 31, cc = tid >> 5;
  const float* Zb = Z + (size_t)b * 262144 + hw0 + hwl;
  float* Ob = out + (size_t)b * 262144 + hw0 + hwl;
  float ls = 0.f;
#pragma unroll 4
  for (int it = 0; it < 32; ++it) {
    const int c = it * 8 + cc;
    const float o = zt[hwl][c];
    const float z = Zb[(size_t)c << 10];
    Ob[(size_t)c << 10] = o;
    const float d = o - z;
    ls = fmaf(d, d, ls);
  }
#pragma unroll
  for (int off = 32; off > 0; off >>= 1) ls += __shfl_down(ls, off);
  __shared__ float red[4];
  if (l == 0) red[w] = ls;
  __syncthreads();
  if (tid == 0)
    atomicAdd(lossSum, (double)((red[0] + red[1]) + (red[2] + red[3])));
}

// ---------------- K6: finalize scalars ----------------
__global__ __launch_bounds__(256) void vq_final(const int* __restrict__ used,
                                                const double* __restrict__ lossSum,
                                                float* __restrict__ out) {
  __shared__ int cnt[256];
  int c = 0;
  for (int k = threadIdx.x; k < 4096; k += 256) c += (used[k] > 0);
  cnt[threadIdx.x] = c;
  __syncthreads();
  if (threadIdx.x == 0) {
    int tot = 0;
    for (int t = 0; t < 256; ++t) tot += cnt[t];
    out[8388608] = (float)(*lossSum * 0.25 / 8388608.0);
    out[8388609] = (float)tot / 4096.0f;
  }
}

extern "C" void kernel_launch(void* const* d_in, const int* in_sizes, int n_in,
                              void* d_out, int out_size, void* d_ws, size_t ws_size,
                              hipStream_t stream) {
  const float* Z = (const float*)d_in[0];
  const float* E = (const float*)d_in[1];
  float* out = (float*)d_out;
  char* w = (char*)d_ws;

  int* idx = (int*)w;                        // 131072 B
  int* flagged = (int*)(w + 131072);         // 131072 B
  float* enorm = (float*)(w + 262144);       // 16384 B
  int* used = (int*)(w + 278528);            // 16384 B [zeroed]
  double* lossSum = (double*)(w + 294912);   // 8 B     [zeroed]
  int* flagCount = (int*)(w + 294920);       // 4 B     [zeroed]

  // d_out doubles as scratch; all regions consumed before vq_out rewrites out.
  char* Epk = (char*)out;                    // 4 MB packed bf16 E (floats [0, 1048576))
  float* pm1 = out + 1048576;                // 2 x 32768
  float* pm2 = out + 1114112;                // 2 x 32768
  int* px = (int*)(out + 1179648);           // 2 x 32768

  hipMemsetAsync(w + 278528, 0, 16384 + 16, stream);
  vq_prep<<<512, 256, 0, stream>>>(E, (uint4*)Epk, enorm);
  vq_screen<<<512, 256, 0, stream>>>(Z, Epk, enorm, pm1, pm2, px);
  vq_merge<<<128, 256, 0, stream>>>(pm1, pm2, px, idx, flagged, flagCount);
  vq_refine<<<256, 256, 0, stream>>>(Z, E, flagged, flagCount, idx);
  vq_out<<<1024, 256, 0, stream>>>(Z, E, idx, out, lossSum, used);
  vq_final<<<1, 256, 0, stream>>>(used, lossSum, out);
}

// Round 5
// 199.613 us; speedup vs baseline: 10.5439x; 1.8500x over previous
//
#include <hip/hip_runtime.h>
#include <math.h>

// VQ-VAE eval forward. z_e [32,256,32,32] fp32, E [4096,256] fp32.
// N = 32768 queries, K = 4096 codes, C = 256.
// Round 5: single fp16-MFMA coarse screen (inputs scaled x256) with top-3
// tracking; window W certifies argmin (|d_err| <= ~0.02 << W/2). Queries with
// top-2 gap < W -> exact fp64 3-way compare; top-3 gap < W ("messy") ->
// chunked fp64 full-row argmin. fp64 is the truth anchor as in rounds 1-4.

#define W 0.05f

using half8 = __attribute__((ext_vector_type(8))) _Float16;
using f32x4 = __attribute__((ext_vector_type(4))) float;

__device__ __forceinline__ void gload_lds16(const void* g, void* l) {
  __builtin_amdgcn_global_load_lds(
      (const __attribute__((address_space(1))) unsigned int*)g,
      (__attribute__((address_space(3))) unsigned int*)l, 16, 0, 0);
}

__device__ __forceinline__ bool lexlt(float v, int x, float ov, int ox) {
  return (v < ov) || (v == ov && x < ox);
}
__device__ __forceinline__ bool lexlt64(double v, int x, double ov, int ox) {
  return (v < ov) || (v == ov && x < ox);
}

// insert (d, c) into sorted top-3 (a0<=a1<=a2); strict < keeps first index
__device__ __forceinline__ void ins3(float d, int c,
                                     float& a0, float& a1, float& a2,
                                     int& b0, int& b1, int& b2) {
  const bool l0 = d < a0, l1 = d < a1, l2 = d < a2;
  a2 = l1 ? a1 : (l2 ? d : a2);
  b2 = l1 ? b1 : (l2 ? c : b2);
  a1 = l0 ? a0 : (l1 ? d : a1);
  b1 = l0 ? b0 : (l1 ? c : b1);
  a0 = l0 ? d : a0;
  b0 = l0 ? c : b0;
}

// merge two sorted triples -> global top-3 (lexicographic on (value,index))
__device__ __forceinline__ void mrg3(float& a0, float& a1, float& a2,
                                     int& x0, int& x1, int& x2,
                                     float b0, float b1, float b2,
                                     int y0, int y1, int y2) {
  const bool A = lexlt(a0, x0, b0, y0);
  const float w0 = A ? a0 : b0; const int w0x = A ? x0 : y0;
  const float fw = A ? a1 : b1; const int fwx = A ? x1 : y1;  // winner's 2nd
  const float ls = A ? b0 : a0; const int lsx = A ? y0 : x0;  // loser's 1st
  const bool B = lexlt(fw, fwx, ls, lsx);
  const float w1 = B ? fw : ls; const int w1x = B ? fwx : lsx;
  const float t1 = A ? a2 : b2; const int t1x = A ? x2 : y2;  // winner's 3rd
  const float l2v = A ? b1 : a1; const int l2x = A ? y1 : x1; // loser's 2nd
  const float c1 = B ? t1 : fw; const int c1x = B ? t1x : fwx;
  const float c2 = B ? ls : l2v; const int c2x = B ? lsx : l2x;
  const bool C = lexlt(c1, c1x, c2, c2x);
  a0 = w0; x0 = w0x; a1 = w1; x1 = w1x;
  a2 = C ? c1 : c2; x2 = C ? c1x : c2x;
}

// ---------------- K1: E -> fp16 (x256) swizzled LDS-image + enorm ----------------
__global__ __launch_bounds__(256) void vq_prep(const float* __restrict__ E,
                                               uint4* __restrict__ Epk,
                                               float* __restrict__ enorm) {
  const int t = blockIdx.x * 256 + threadIdx.x;   // 131072 = 4096 codes x 32 octets
  const int code = t >> 5, jj = t & 31;
  const int slice = jj >> 3, j = jj & 7;
  const int cg = code >> 7, c = code & 127;
  const float* src = E + (size_t)code * 256 + jj * 8;
  union { half8 h; uint4 u; } pk;
  float s = 0.f;
#pragma unroll
  for (int e = 0; e < 8; ++e) {
    const float z = src[e];
    s = fmaf(z, z, s);
    pk.h[e] = (_Float16)(z * 256.0f);
  }
  const size_t g = (size_t)((cg * 4 + slice) * 1024) + c * 8 + (j ^ (c & 7));
  Epk[g] = pk.u;
#pragma unroll
  for (int off = 1; off < 32; off <<= 1) s += __shfl_xor(s, off);
  if (jj == 0) enorm[code] = s;
}

// ---------------- K2: fp16 MFMA coarse screen with top-3 ----------------
// grid 512 = 256 query-groups (128 q) x 2 code-halves; 4 waves x 32 q.
// 32KB superslices (128 codes x 128 k), dbuf; 2 blocks/CU.
__global__ __launch_bounds__(256, 2) void vq_screen(
    const float* __restrict__ Z, const char* __restrict__ Epk,
    const float* __restrict__ enorm,
    float* __restrict__ pv0, float* __restrict__ pv1, float* __restrict__ pv2,
    int* __restrict__ pi0, int* __restrict__ pi1, int* __restrict__ pi2) {
  __shared__ char lds[65536];
  const int tid = threadIdx.x;
  const int w = tid >> 6, l = tid & 63;
  const int qg = blockIdx.x >> 1, half = blockIdx.x & 1;
  const int qbase = qg * 128;
  const int b = qbase >> 10;
  const int hwq = (qbase & 1023) + w * 32 + (l & 15);

  // A-frags: fp16(z*256), 2 query-tiles x K=256
  const float* Zq = Z + (size_t)b * 262144 + hwq;
  half8 ah[2][8];
#pragma unroll
  for (int u = 0; u < 2; ++u)
#pragma unroll
    for (int ks = 0; ks < 8; ++ks) {
      const int c0 = ks * 32 + (l >> 4) * 8;
#pragma unroll
      for (int e = 0; e < 8; ++e)
        ah[u][ks][e] = (_Float16)(Zq[u * 16 + ((size_t)(c0 + e) << 10)] * 256.0f);
    }

  // swizzled LDS read offsets: s = k-step within superslice (4 x 32k)
  int lo[4];
#pragma unroll
  for (int s = 0; s < 4; ++s)
    lo[s] = (s >> 1) * 16384 + (l & 15) * 128 +
            ((((s & 1) * 4 + (l >> 4)) ^ (l & 7)) << 4);

  float m0[2][4], m1[2][4], m2[2][4];
  int x0[2][4], x1[2][4], x2[2][4];
#pragma unroll
  for (int u = 0; u < 2; ++u)
#pragma unroll
    for (int r = 0; r < 4; ++r) {
      m0[u][r] = INFINITY; m1[u][r] = INFINITY; m2[u][r] = INFINITY;
      x0[u][r] = 0x7fffffff; x1[u][r] = 0x7fffffff; x2[u][r] = 0x7fffffff;
    }

  const int sbase = half * 32;   // 32 superslices of 32KB per half
  auto stage = [&](int sel, int ss) {
    const char* src = Epk + ((size_t)(sbase + ss) << 15) + w * 8192 + l * 16;
    char* dst = lds + sel * 32768 + w * 8192;   // linear dest (rule 21)
#pragma unroll
    for (int i = 0; i < 8; ++i) gload_lds16(src + i * 1024, dst + i * 1024);
  };
  stage(0, 0);

  for (int chunk = 0; chunk < 16; ++chunk) {
    f32x4 acc[2][8];
#pragma unroll
    for (int u = 0; u < 2; ++u)
#pragma unroll
      for (int t = 0; t < 8; ++t) acc[u][t] = (f32x4){0.f, 0.f, 0.f, 0.f};

    for (int h = 0; h < 2; ++h) {
      const int ss = chunk * 2 + h;
      __syncthreads();
      if (ss + 1 < 32) stage((ss + 1) & 1, ss + 1);   // prefetch next superslice
      const char* Lb = lds + (ss & 1) * 32768;
      __builtin_amdgcn_s_setprio(1);
#pragma unroll
      for (int s = 0; s < 4; ++s) {
        const int ksg = h * 4 + s;
#pragma unroll
        for (int t = 0; t < 8; ++t) {
          const half8 eh = *(const half8*)(Lb + t * 2048 + lo[s]);
          acc[0][t] = __builtin_amdgcn_mfma_f32_16x16x32_f16(ah[0][ksg], eh, acc[0][t], 0, 0, 0);
          acc[1][t] = __builtin_amdgcn_mfma_f32_16x16x32_f16(ah[1][ksg], eh, acc[1][t], 0, 0, 0);
        }
      }
      __builtin_amdgcn_s_setprio(0);
    }

    // epilogue: d = enorm - 2*dot/65536; running top-3
    const int cb = half * 2048 + chunk * 128;
#pragma unroll
    for (int t = 0; t < 8; ++t) {
      const int code = cb + t * 16 + (l & 15);
      const float en = enorm[code];
#pragma unroll
      for (int u = 0; u < 2; ++u)
#pragma unroll
        for (int r = 0; r < 4; ++r) {
          const float d = fmaf(acc[u][t][r], -3.0517578125e-05f, en);
          ins3(d, code, m0[u][r], m1[u][r], m2[u][r], x0[u][r], x1[u][r], x2[u][r]);
        }
    }
  }

  // cross-lane top-3 merge over the 16 lanes sharing each row-group
#pragma unroll
  for (int mask = 1; mask <= 8; mask <<= 1) {
#pragma unroll
    for (int u = 0; u < 2; ++u)
#pragma unroll
      for (int r = 0; r < 4; ++r) {
        const float o0 = __shfl_xor(m0[u][r], mask);
        const float o1 = __shfl_xor(m1[u][r], mask);
        const float o2 = __shfl_xor(m2[u][r], mask);
        const int y0 = __shfl_xor(x0[u][r], mask);
        const int y1 = __shfl_xor(x1[u][r], mask);
        const int y2 = __shfl_xor(x2[u][r], mask);
        mrg3(m0[u][r], m1[u][r], m2[u][r], x0[u][r], x1[u][r], x2[u][r],
             o0, o1, o2, y0, y1, y2);
      }
  }
  if ((l & 15) == 0) {
#pragma unroll
    for (int u = 0; u < 2; ++u)
#pragma unroll
      for (int r = 0; r < 4; ++r) {
        const int n = qbase + w * 32 + u * 16 + (l >> 4) * 4 + r;
        const int o = half * 32768 + n;
        pv0[o] = m0[u][r]; pv1[o] = m1[u][r]; pv2[o] = m2[u][r];
        pi0[o] = x0[u][r]; pi1[o] = x1[u][r]; pi2[o] = x2[u][r];
      }
  }
}

// ---------------- K3: merge halves, classify ----------------
__global__ __launch_bounds__(256) void vq_merge(
    float* __restrict__ pv0, float* __restrict__ pv1, float* __restrict__ pv2,
    int* __restrict__ pi0, int* __restrict__ pi1, int* __restrict__ pi2,
    int* __restrict__ idxOut, int* __restrict__ cand, int* __restrict__ candCount,
    int* __restrict__ messy, int* __restrict__ messyCount) {
  const int n = blockIdx.x * 256 + threadIdx.x;
  float a0 = pv0[n], a1 = pv1[n], a2 = pv2[n];
  int x0 = pi0[n], x1 = pi1[n], x2 = pi2[n];
  mrg3(a0, a1, a2, x0, x1, x2,
       pv0[n + 32768], pv1[n + 32768], pv2[n + 32768],
       pi0[n + 32768], pi1[n + 32768], pi2[n + 32768]);
  idxOut[n] = x0;                 // provisional (final if unflagged)
  pi0[n] = x0; pi1[n] = x1; pi2[n] = x2;   // merged triple for cand3
  if (a1 - a0 < W) {
    if (a2 - a0 < W) {
      const int p = atomicAdd(messyCount, 1);
      if (p < 2048) messy[p] = n;
    } else {
      const int p = atomicAdd(candCount, 1);
      cand[p] = n;
    }
  }
}

// ---------------- K4: fp64 exact 3-way compare (one wave per query) ----------------
__global__ __launch_bounds__(256) void vq_cand3(
    const float* __restrict__ Z, const float* __restrict__ E,
    const int* __restrict__ pi0, const int* __restrict__ pi1,
    const int* __restrict__ pi2, const int* __restrict__ cand,
    const int* __restrict__ candCount, int* __restrict__ idxOut) {
  const int w = threadIdx.x >> 6, l = threadIdx.x & 63;
  const int cnt = *candCount;
  for (int j = blockIdx.x * 4 + w; j < cnt; j += gridDim.x * 4) {
    const int n = cand[j];
    const int b = n >> 10, hw = n & 1023;
    const int ca = pi0[n], cbn = pi1[n], cc = pi2[n];
    float z4[4];
#pragma unroll
    for (int i = 0; i < 4; ++i)
      z4[i] = Z[(size_t)b * 262144 + ((size_t)(l * 4 + i) << 10) + hw];
    const float4 e0 = *(const float4*)(E + (size_t)ca * 256 + l * 4);
    const float4 e1 = *(const float4*)(E + (size_t)cbn * 256 + l * 4);
    const float4 e2 = *(const float4*)(E + (size_t)cc * 256 + l * 4);
    double d0 = 0, d1 = 0, d2 = 0;
    const float* p0 = (const float*)&e0;
    const float* p1 = (const float*)&e1;
    const float* p2 = (const float*)&e2;
#pragma unroll
    for (int i = 0; i < 4; ++i) {
      const double f0 = (double)z4[i] - (double)p0[i];
      const double f1 = (double)z4[i] - (double)p1[i];
      const double f2 = (double)z4[i] - (double)p2[i];
      d0 = fma(f0, f0, d0);
      d1 = fma(f1, f1, d1);
      d2 = fma(f2, f2, d2);
    }
#pragma unroll
    for (int off = 32; off > 0; off >>= 1) {
      d0 += __shfl_down(d0, off);
      d1 += __shfl_down(d1, off);
      d2 += __shfl_down(d2, off);
    }
    if (l == 0) {
      double bv = d0; int bx = ca;
      if (lexlt64(d1, cbn, bv, bx)) { bv = d1; bx = cbn; }
      if (lexlt64(d2, cc, bv, bx)) { bv = d2; bx = cc; }
      idxOut[n] = bx;
    }
  }
}

// ---------------- K5: fp64 full-row partial argmin for messy queries ----------------
// job = (group of 4 messy queries, 256-code chunk); 256 KB E per block max.
__global__ __launch_bounds__(256) void vq_messy1(
    const float* __restrict__ Z, const float* __restrict__ E,
    const int* __restrict__ messy, const int* __restrict__ messyCount,
    double* __restrict__ parv, int* __restrict__ parx) {
  __shared__ float zs[4][256];
  __shared__ double rv[4][256];
  __shared__ int ri[4][256];
  const int cnt0 = *messyCount;
  const int cnt = cnt0 > 2048 ? 2048 : cnt0;
  const int jobs = ((cnt + 3) >> 2) * 16;
  const int t = threadIdx.x;
  for (int job = blockIdx.x; job < jobs; job += gridDim.x) {
    const int grp = job >> 4, chunk = job & 15;
    __syncthreads();
    {
      const int q = t >> 6, lq = t & 63;
      const int mi = grp * 4 + q;
      const int n = messy[mi < cnt ? mi : grp * 4];
      const int b = n >> 10, hw = n & 1023;
#pragma unroll
      for (int i = 0; i < 4; ++i)
        zs[q][lq * 4 + i] =
            Z[(size_t)b * 262144 + ((size_t)(lq * 4 + i) << 10) + hw];
    }
    __syncthreads();
    const int code = chunk * 256 + t;
    const float* er = E + (size_t)code * 256;
    double s0 = 0, s1 = 0, s2 = 0, s3 = 0;
    for (int c = 0; c < 256; ++c) {
      const double ec = (double)er[c];
      const double f0 = (double)zs[0][c] - ec;
      const double f1 = (double)zs[1][c] - ec;
      const double f2 = (double)zs[2][c] - ec;
      const double f3 = (double)zs[3][c] - ec;
      s0 = fma(f0, f0, s0);
      s1 = fma(f1, f1, s1);
      s2 = fma(f2, f2, s2);
      s3 = fma(f3, f3, s3);
    }
    rv[0][t] = s0; rv[1][t] = s1; rv[2][t] = s2; rv[3][t] = s3;
    ri[0][t] = code; ri[1][t] = code; ri[2][t] = code; ri[3][t] = code;
    __syncthreads();
    for (int s = 128; s > 0; s >>= 1) {
      if (t < s) {
#pragma unroll
        for (int qq = 0; qq < 4; ++qq)
          if (lexlt64(rv[qq][t + s], ri[qq][t + s], rv[qq][t], ri[qq][t])) {
            rv[qq][t] = rv[qq][t + s];
            ri[qq][t] = ri[qq][t + s];
          }
      }
      __syncthreads();
    }
    if (t == 0) {
#pragma unroll
      for (int qq = 0; qq < 4; ++qq) {
        const int mi = grp * 4 + qq;
        if (mi < cnt) {
          parv[mi * 16 + chunk] = rv[qq][0];
          parx[mi * 16 + chunk] = ri[qq][0];
        }
      }
    }
  }
}

// ---------------- K6: merge messy partials ----------------
__global__ __launch_bounds__(256) void vq_messy2(
    const int* __restrict__ messy, const int* __restrict__ messyCount,
    const double* __restrict__ parv, const int* __restrict__ parx,
    int* __restrict__ idxOut) {
  const int cnt0 = *messyCount;
  const int cnt = cnt0 > 2048 ? 2048 : cnt0;
  for (int j = blockIdx.x * 256 + threadIdx.x; j < cnt; j += gridDim.x * 256) {
    double bv = parv[j * 16];
    int bx = parx[j * 16];
    for (int ch = 1; ch < 16; ++ch) {
      const double v = parv[j * 16 + ch];
      const int x = parx[j * 16 + ch];
      if (lexlt64(v, x, bv, bx)) { bv = v; bx = x; }
    }
    idxOut[messy[j]] = bx;
  }
}

// ---------------- K7: row-gather z_q + loss + used marking ----------------
__global__ __launch_bounds__(256) void vq_out(
    const float* __restrict__ Z, const float* __restrict__ E,
    const int* __restrict__ idx, float* __restrict__ out,
    double* __restrict__ lossSum, int* __restrict__ used) {
  __shared__ float zt[32][257];
  __shared__ int ids[32];
  const int tid = threadIdx.x;
  const int qb = blockIdx.x * 32;
  const int b = qb >> 10, hw0 = qb & 1023;
  if (tid < 32) {
    const int id = idx[qb + tid];
    ids[tid] = id;
    used[id] = 1;
  }
  __syncthreads();
  const int w = tid >> 6, l = tid & 63;
#pragma unroll
  for (int rr = 0; rr < 8; ++rr) {
    const int q = rr * 4 + w;
    const float4 v = *(const float4*)(E + (size_t)ids[q] * 256 + l * 4);
    zt[q][l * 4 + 0] = v.x;
    zt[q][l * 4 + 1] = v.y;
    zt[q][l * 4 + 2] = v.z;
    zt[q][l * 4 + 3] = v.w;
  }
  __syncthreads();
  const int hwl = tid & 31, cc = tid >> 5;
  const float* Zb = Z + (size_t)b * 262144 + hw0 + hwl;
  float* Ob = out + (size_t)b * 262144 + hw0 + hwl;
  float ls = 0.f;
#pragma unroll 4
  for (int it = 0; it < 32; ++it) {
    const int c = it * 8 + cc;
    const float o = zt[hwl][c];
    const float z = Zb[(size_t)c << 10];
    Ob[(size_t)c << 10] = o;
    const float d = o - z;
    ls = fmaf(d, d, ls);
  }
#pragma unroll
  for (int off = 32; off > 0; off >>= 1) ls += __shfl_down(ls, off);
  __shared__ float red[4];
  if (l == 0) red[w] = ls;
  __syncthreads();
  if (tid == 0)
    atomicAdd(lossSum, (double)((red[0] + red[1]) + (red[2] + red[3])));
}

// ---------------- K8: finalize scalars ----------------
__global__ __launch_bounds__(256) void vq_final(const int* __restrict__ used,
                                                const double* __restrict__ lossSum,
                                                float* __restrict__ out) {
  __shared__ int cnt[256];
  int c = 0;
  for (int k = threadIdx.x; k < 4096; k += 256) c += (used[k] > 0);
  cnt[threadIdx.x] = c;
  __syncthreads();
  if (threadIdx.x == 0) {
    int tot = 0;
    for (int t = 0; t < 256; ++t) tot += cnt[t];
    out[8388608] = (float)(*lossSum * 0.25 / 8388608.0);
    out[8388609] = (float)tot / 4096.0f;
  }
}

extern "C" void kernel_launch(void* const* d_in, const int* in_sizes, int n_in,
                              void* d_out, int out_size, void* d_ws, size_t ws_size,
                              hipStream_t stream) {
  const float* Z = (const float*)d_in[0];
  const float* E = (const float*)d_in[1];
  float* out = (float*)d_out;
  char* w = (char*)d_ws;

  // ws (same footprint as prior rounds)
  int* idx = (int*)w;                         // 128 KB
  int* cand = (int*)(w + 131072);             // 128 KB
  float* enorm = (float*)(w + 262144);        // 16 KB
  int* used = (int*)(w + 278528);             // 16 KB [zeroed]
  double* lossSum = (double*)(w + 294912);    // 8 B   [zeroed]
  int* candCount = (int*)(w + 294920);        // 4 B   [zeroed]
  int* messyCount = (int*)(w + 294924);       // 4 B   [zeroed]

  // d_out doubles as scratch; all consumed before vq_out rewrites out.
  char* Epk16 = (char*)out;                   // 2 MB fp16 image (floats [0,524288))
  float* pv0 = out + 524288;
  float* pv1 = out + 589824;
  float* pv2 = out + 655360;
  int* pi0 = (int*)(out + 720896);
  int* pi1 = (int*)(out + 786432);
  int* pi2 = (int*)(out + 851968);
  int* messy = (int*)(out + 917504);          // 2048 ints
  double* parv = (double*)(out + 919552);     // 32768 doubles
  int* parx = (int*)(out + 985088);           // 32768 ints

  hipMemsetAsync(w + 278528, 0, 16400, stream);
  vq_prep<<<512, 256, 0, stream>>>(E, (uint4*)Epk16, enorm);
  vq_screen<<<512, 256, 0, stream>>>(Z, Epk16, enorm, pv0, pv1, pv2, pi0, pi1, pi2);
  vq_merge<<<128, 256, 0, stream>>>(pv0, pv1, pv2, pi0, pi1, pi2, idx, cand,
                                    candCount, messy, messyCount);
  vq_cand3<<<256, 256, 0, stream>>>(Z, E, pi0, pi1, pi2, cand, candCount, idx);
  vq_messy1<<<1024, 256, 0, stream>>>(Z, E, messy, messyCount, parv, parx);
  vq_messy2<<<8, 256, 0, stream>>>(messy, messyCount, parv, parx, idx);
  vq_out<<<1024, 256, 0, stream>>>(Z, E, idx, out, lossSum, used);
  vq_final<<<1, 256, 0, stream>>>(used, lossSum, out);
}

// Round 6
// 186.098 us; speedup vs baseline: 11.3096x; 1.0726x over previous
//
#include <hip/hip_runtime.h>
#include <math.h>

// VQ-VAE eval forward. z_e [32,256,32,32] fp32, E [4096,256] fp32.
// N = 32768 queries, K = 4096 codes, C = 256.
// Round 6: fp16-MFMA screen with packed-int top-3 keys
//   key = (trunc(d*1024) << 12) | code   (monotone; first-index tie-break free)
// 4 code-quarters (grid 1024), 16KB slices, 3 blocks/CU. Flag if int-gap < 52
// (=0.0508 > 2*e_screen~0.043): top-2 near -> exact fp64 3-way (cand3);
// top-3 near -> chunked fp64 full-row argmin (messy). fp64 = truth anchor.

#define WGAP 52   // quantized-distance window (units of 1/1024)

using half8 = __attribute__((ext_vector_type(8))) _Float16;
using f32x4 = __attribute__((ext_vector_type(4))) float;

__device__ __forceinline__ void gload_lds16(const void* g, void* l) {
  __builtin_amdgcn_global_load_lds(
      (const __attribute__((address_space(1))) unsigned int*)g,
      (__attribute__((address_space(3))) unsigned int*)l, 16, 0, 0);
}

__device__ __forceinline__ bool lexlt64(double v, int x, double ov, int ox) {
  return (v < ov) || (v == ov && x < ox);
}

// insert key into sorted triple (a0<=a1<=a2): 5 min/max ops, branchless
__device__ __forceinline__ void ins3k(int key, int& a0, int& a1, int& a2) {
  const int mx0 = max(key, a0);
  a0 = min(key, a0);
  const int mx1 = max(mx0, a1);
  a1 = min(mx0, a1);
  a2 = min(mx1, a2);
}

// merge two sorted triples -> smallest 3 of union: 7 min/max ops
__device__ __forceinline__ void mrg3k(int& a0, int& a1, int& a2,
                                      int b0, int b1, int b2) {
  const int c0 = min(a0, b0);
  const int x = max(a0, b0);
  const int y = min(a1, b1);
  const int c1 = min(x, y);
  const int z = max(x, y);
  const int ww = min(a2, b2);
  const int c2 = min(z, ww);
  a0 = c0; a1 = c1; a2 = c2;
}

// ---------------- K1: E -> fp16(x256) swizzled slice image + enorm*1024 ----------------
// Slice = 64 codes x 128 k = 16KB. granule(16B) = slice*1024 + rc*16 + (jo ^ (rc&15))
//   slice = quarter*32 + c16*2 + khalf;  rc = code&63;  jo = k-octet within half
__global__ __launch_bounds__(256) void vq_prep(const float* __restrict__ E,
                                               uint4* __restrict__ Epk,
                                               float* __restrict__ en1024) {
  const int t = blockIdx.x * 256 + threadIdx.x;   // 131072 = 4096 codes x 32 octets
  const int code = t >> 5, j = t & 31;
  const int quarter = code >> 10, c16 = (code >> 6) & 15, rc = code & 63;
  const int khalf = j >> 4, jo = j & 15;
  const float* src = E + (size_t)code * 256 + j * 8;
  union { half8 h; uint4 u; } pk;
  float s = 0.f;
#pragma unroll
  for (int e = 0; e < 8; ++e) {
    const float z = src[e];
    s = fmaf(z, z, s);
    pk.h[e] = (_Float16)(z * 256.0f);
  }
  const size_t g = (size_t)(quarter * 32 + c16 * 2 + khalf) * 1024 +
                   rc * 16 + (jo ^ (rc & 15));
  Epk[g] = pk.u;
#pragma unroll
  for (int off = 1; off < 32; off <<= 1) s += __shfl_xor(s, off);
  if (j == 0) en1024[code] = s * 1024.0f;
}

// ---------------- K2: fp16 MFMA screen, packed-int top-3 ----------------
// grid 1024 = 256 query-groups (128 q) x 4 code-quarters (1024 codes).
// 4 waves x 32 q (2 tiles); 16KB dbuf slices; 3 blocks/CU.
__global__ __launch_bounds__(256, 3) void vq_screen(
    const float* __restrict__ Z, const char* __restrict__ Epk,
    const float* __restrict__ en1024,
    int* __restrict__ pk0, int* __restrict__ pk1, int* __restrict__ pk2) {
  __shared__ char lds[32768];
  const int tid = threadIdx.x;
  const int w = tid >> 6, l = tid & 63;
  const int qg = blockIdx.x >> 2, quarter = blockIdx.x & 3;
  const int qbase = qg * 128;
  const int b = qbase >> 10;
  const int hwq = (qbase & 1023) + w * 32 + (l & 15);

  // A-frags: fp16(z*256), 2 query-tiles x K=256
  const float* Zq = Z + (size_t)b * 262144 + hwq;
  half8 ah[2][8];
#pragma unroll
  for (int u = 0; u < 2; ++u)
#pragma unroll
    for (int ks = 0; ks < 8; ++ks) {
      const int c0 = ks * 32 + (l >> 4) * 8;
#pragma unroll
      for (int e = 0; e < 8; ++e)
        ah[u][ks][e] = (_Float16)(Zq[u * 16 + ((size_t)(c0 + e) << 10)] * 256.0f);
    }

  // swizzled LDS read offsets (within 4KB code-tile row block)
  int lo[4];
#pragma unroll
  for (int s = 0; s < 4; ++s)
    lo[s] = (l & 15) * 256 + (((s * 4 + (l >> 4)) ^ (l & 15)) << 4);

  int k0[2][4], k1[2][4], k2[2][4];
#pragma unroll
  for (int u = 0; u < 2; ++u)
#pragma unroll
    for (int r = 0; r < 4; ++r) {
      k0[u][r] = 0x7fffffff; k1[u][r] = 0x7fffffff; k2[u][r] = 0x7fffffff;
    }

  auto stage = [&](int sel, int ss) {
    const char* src = Epk + ((size_t)(quarter * 32 + ss) << 14) + w * 4096 + l * 16;
    char* dst = lds + sel * 16384 + w * 4096;   // linear dest (rule 21)
#pragma unroll
    for (int i = 0; i < 4; ++i) gload_lds16(src + i * 1024, dst + i * 1024);
  };
  stage(0, 0);

  for (int chunk = 0; chunk < 16; ++chunk) {
    f32x4 acc[2][4];
#pragma unroll
    for (int u = 0; u < 2; ++u)
#pragma unroll
      for (int t = 0; t < 4; ++t) acc[u][t] = (f32x4){0.f, 0.f, 0.f, 0.f};

#pragma unroll
    for (int sh = 0; sh < 2; ++sh) {
      const int ss = chunk * 2 + sh;
      __syncthreads();                                // current buffer ready
      if (ss + 1 < 32) stage((ss + 1) & 1, ss + 1);   // async prefetch next
      const char* Lb = lds + (ss & 1) * 16384;
      __builtin_amdgcn_s_setprio(1);
#pragma unroll
      for (int s = 0; s < 4; ++s) {
        const int ks = sh * 4 + s;
#pragma unroll
        for (int t = 0; t < 4; ++t) {
          const half8 eh = *(const half8*)(Lb + t * 4096 + lo[s]);
          acc[0][t] = __builtin_amdgcn_mfma_f32_16x16x32_f16(ah[0][ks], eh, acc[0][t], 0, 0, 0);
          acc[1][t] = __builtin_amdgcn_mfma_f32_16x16x32_f16(ah[1][ks], eh, acc[1][t], 0, 0, 0);
        }
      }
      __builtin_amdgcn_s_setprio(0);
    }

    // epilogue: d*1024 = en1024 - acc*(2*1024/65536); pack key; 5-op insert
    const int cb = quarter * 1024 + chunk * 64;
#pragma unroll
    for (int t = 0; t < 4; ++t) {
      const int code = cb + t * 16 + (l & 15);
      const float en = en1024[code];
#pragma unroll
      for (int u = 0; u < 2; ++u)
#pragma unroll
        for (int r = 0; r < 4; ++r) {
          const float df = fmaf(acc[u][t][r], -0.03125f, en);
          const int di = (int)df;                       // trunc: monotone
          const int key = (int)(((unsigned)di << 12) + (unsigned)code);
          ins3k(key, k0[u][r], k1[u][r], k2[u][r]);
        }
    }
  }

  // cross-lane top-3 merge over the 16 lanes sharing each row-group
#pragma unroll
  for (int mask = 1; mask <= 8; mask <<= 1) {
#pragma unroll
    for (int u = 0; u < 2; ++u)
#pragma unroll
      for (int r = 0; r < 4; ++r) {
        const int o0 = __shfl_xor(k0[u][r], mask);
        const int o1 = __shfl_xor(k1[u][r], mask);
        const int o2 = __shfl_xor(k2[u][r], mask);
        mrg3k(k0[u][r], k1[u][r], k2[u][r], o0, o1, o2);
      }
  }
  if ((l & 15) == 0) {
#pragma unroll
    for (int u = 0; u < 2; ++u)
#pragma unroll
      for (int r = 0; r < 4; ++r) {
        const int n = qbase + w * 32 + u * 16 + (l >> 4) * 4 + r;
        const int o = quarter * 32768 + n;
        pk0[o] = k0[u][r]; pk1[o] = k1[u][r]; pk2[o] = k2[u][r];
      }
  }
}

// ---------------- K3: merge 4 quarters, classify ----------------
__global__ __launch_bounds__(256) void vq_merge(
    const int* __restrict__ pk0, const int* __restrict__ pk1,
    const int* __restrict__ pk2, int* __restrict__ idxOut,
    int* __restrict__ cand, int* __restrict__ candCount,
    int* __restrict__ messy, int* __restrict__ messyCount,
    int* __restrict__ pi0, int* __restrict__ pi1, int* __restrict__ pi2) {
  const int n = blockIdx.x * 256 + threadIdx.x;
  int a0 = pk0[n], a1 = pk1[n], a2 = pk2[n];
#pragma unroll
  for (int q = 1; q < 4; ++q) {
    const int o = q * 32768 + n;
    mrg3k(a0, a1, a2, pk0[o], pk1[o], pk2[o]);
  }
  const int x0 = a0 & 0xfff;
  idxOut[n] = x0;                       // final unless flagged
  const int d0 = a0 >> 12, d1 = a1 >> 12, d2 = a2 >> 12;
  if (d1 - d0 < WGAP) {
    if (d2 - d0 < WGAP) {
      const int p = atomicAdd(messyCount, 1);
      if (p < 4096) messy[p] = n;
    } else {
      const int p = atomicAdd(candCount, 1);
      cand[p] = n;
      pi0[n] = x0; pi1[n] = a1 & 0xfff; pi2[n] = a2 & 0xfff;
    }
  }
}

// ---------------- K4: fp64 exact 3-way compare (one wave per query) ----------------
__global__ __launch_bounds__(256) void vq_cand3(
    const float* __restrict__ Z, const float* __restrict__ E,
    const int* __restrict__ pi0, const int* __restrict__ pi1,
    const int* __restrict__ pi2, const int* __restrict__ cand,
    const int* __restrict__ candCount, int* __restrict__ idxOut) {
  const int w = threadIdx.x >> 6, l = threadIdx.x & 63;
  const int cnt = *candCount;
  for (int j = blockIdx.x * 4 + w; j < cnt; j += gridDim.x * 4) {
    const int n = cand[j];
    const int b = n >> 10, hw = n & 1023;
    const int ca = pi0[n], cbn = pi1[n], cc = pi2[n];
    float z4[4];
#pragma unroll
    for (int i = 0; i < 4; ++i)
      z4[i] = Z[(size_t)b * 262144 + ((size_t)(l * 4 + i) << 10) + hw];
    const float4 e0 = *(const float4*)(E + (size_t)ca * 256 + l * 4);
    const float4 e1 = *(const float4*)(E + (size_t)cbn * 256 + l * 4);
    const float4 e2 = *(const float4*)(E + (size_t)cc * 256 + l * 4);
    double d0 = 0, d1 = 0, d2 = 0;
    const float* p0 = (const float*)&e0;
    const float* p1 = (const float*)&e1;
    const float* p2 = (const float*)&e2;
#pragma unroll
    for (int i = 0; i < 4; ++i) {
      const double f0 = (double)z4[i] - (double)p0[i];
      const double f1 = (double)z4[i] - (double)p1[i];
      const double f2 = (double)z4[i] - (double)p2[i];
      d0 = fma(f0, f0, d0);
      d1 = fma(f1, f1, d1);
      d2 = fma(f2, f2, d2);
    }
#pragma unroll
    for (int off = 32; off > 0; off >>= 1) {
      d0 += __shfl_down(d0, off);
      d1 += __shfl_down(d1, off);
      d2 += __shfl_down(d2, off);
    }
    if (l == 0) {
      double bv = d0; int bx = ca;
      if (lexlt64(d1, cbn, bv, bx)) { bv = d1; bx = cbn; }
      if (lexlt64(d2, cc, bv, bx)) { bv = d2; bx = cc; }
      idxOut[n] = bx;
    }
  }
}

// ---------------- K5: fp64 full-row partial argmin for messy queries ----------------
__global__ __launch_bounds__(256) void vq_messy1(
    const float* __restrict__ Z, const float* __restrict__ E,
    const int* __restrict__ messy, const int* __restrict__ messyCount,
    double* __restrict__ parv, int* __restrict__ parx) {
  __shared__ float zs[4][256];
  __shared__ double rv[4][256];
  __shared__ int ri[4][256];
  const int cnt0 = *messyCount;
  const int cnt = cnt0 > 4096 ? 4096 : cnt0;
  const int jobs = ((cnt + 3) >> 2) * 16;
  const int t = threadIdx.x;
  for (int job = blockIdx.x; job < jobs; job += gridDim.x) {
    const int grp = job >> 4, chunk = job & 15;
    __syncthreads();
    {
      const int q = t >> 6, lq = t & 63;
      const int mi = grp * 4 + q;
      const int n = messy[mi < cnt ? mi : grp * 4];
      const int b = n >> 10, hw = n & 1023;
#pragma unroll
      for (int i = 0; i < 4; ++i)
        zs[q][lq * 4 + i] =
            Z[(size_t)b * 262144 + ((size_t)(lq * 4 + i) << 10) + hw];
    }
    __syncthreads();
    const int code = chunk * 256 + t;
    const float* er = E + (size_t)code * 256;
    double s0 = 0, s1 = 0, s2 = 0, s3 = 0;
    for (int c = 0; c < 256; ++c) {
      const double ec = (double)er[c];
      const double f0 = (double)zs[0][c] - ec;
      const double f1 = (double)zs[1][c] - ec;
      const double f2 = (double)zs[2][c] - ec;
      const double f3 = (double)zs[3][c] - ec;
      s0 = fma(f0, f0, s0);
      s1 = fma(f1, f1, s1);
      s2 = fma(f2, f2, s2);
      s3 = fma(f3, f3, s3);
    }
    rv[0][t] = s0; rv[1][t] = s1; rv[2][t] = s2; rv[3][t] = s3;
    ri[0][t] = code; ri[1][t] = code; ri[2][t] = code; ri[3][t] = code;
    __syncthreads();
    for (int s = 128; s > 0; s >>= 1) {
      if (t < s) {
#pragma unroll
        for (int qq = 0; qq < 4; ++qq)
          if (lexlt64(rv[qq][t + s], ri[qq][t + s], rv[qq][t], ri[qq][t])) {
            rv[qq][t] = rv[qq][t + s];
            ri[qq][t] = ri[qq][t + s];
          }
      }
      __syncthreads();
    }
    if (t == 0) {
#pragma unroll
      for (int qq = 0; qq < 4; ++qq) {
        const int mi = grp * 4 + qq;
        if (mi < cnt) {
          parv[mi * 16 + chunk] = rv[qq][0];
          parx[mi * 16 + chunk] = ri[qq][0];
        }
      }
    }
  }
}

// ---------------- K6: merge messy partials ----------------
__global__ __launch_bounds__(256) void vq_messy2(
    const int* __restrict__ messy, const int* __restrict__ messyCount,
    const double* __restrict__ parv, const int* __restrict__ parx,
    int* __restrict__ idxOut) {
  const int cnt0 = *messyCount;
  const int cnt = cnt0 > 4096 ? 4096 : cnt0;
  for (int j = blockIdx.x * 256 + threadIdx.x; j < cnt; j += gridDim.x * 256) {
    double bv = parv[j * 16];
    int bx = parx[j * 16];
    for (int ch = 1; ch < 16; ++ch) {
      const double v = parv[j * 16 + ch];
      const int x = parx[j * 16 + ch];
      if (lexlt64(v, x, bv, bx)) { bv = v; bx = x; }
    }
    idxOut[messy[j]] = bx;
  }
}

// ---------------- K7: row-gather z_q + loss + used marking ----------------
__global__ __launch_bounds__(256) void vq_out(
    const float* __restrict__ Z, const float* __restrict__ E,
    const int* __restrict__ idx, float* __restrict__ out,
    double* __restrict__ lossSum, int* __restrict__ used) {
  __shared__ float zt[32][257];
  __shared__ int ids[32];
  const int tid = threadIdx.x;
  const int qb = blockIdx.x * 32;
  const int b = qb >> 10, hw0 = qb & 1023;
  if (tid < 32) {
    const int id = idx[qb + tid];
    ids[tid] = id;
    used[id] = 1;
  }
  __syncthreads();
  const int w = tid >> 6, l = tid & 63;
#pragma unroll
  for (int rr = 0; rr < 8; ++rr) {
    const int q = rr * 4 + w;
    const float4 v = *(const float4*)(E + (size_t)ids[q] * 256 + l * 4);
    zt[q][l * 4 + 0] = v.x;
    zt[q][l * 4 + 1] = v.y;
    zt[q][l * 4 + 2] = v.z;
    zt[q][l * 4 + 3] = v.w;
  }
  __syncthreads();
  const int hwl = tid & 31, cc = tid >> 5;
  const float* Zb = Z + (size_t)b * 262144 + hw0 + hwl;
  float* Ob = out + (size_t)b * 262144 + hw0 + hwl;
  float ls = 0.f;
#pragma unroll 4
  for (int it = 0; it < 32; ++it) {
    const int c = it * 8 + cc;
    const float o = zt[hwl][c];
    const float z = Zb[(size_t)c << 10];
    Ob[(size_t)c << 10] = o;
    const float d = o - z;
    ls = fmaf(d, d, ls);
  }
#pragma unroll
  for (int off = 32; off > 0; off >>= 1) ls += __shfl_down(ls, off);
  __shared__ float red[4];
  if (l == 0) red[w] = ls;
  __syncthreads();
  if (tid == 0)
    atomicAdd(lossSum, (double)((red[0] + red[1]) + (red[2] + red[3])));
}

// ---------------- K8: finalize scalars ----------------
__global__ __launch_bounds__(256) void vq_final(const int* __restrict__ used,
                                                const double* __restrict__ lossSum,
                                                float* __restrict__ out) {
  __shared__ int cnt[256];
  int c = 0;
  for (int k = threadIdx.x; k < 4096; k += 256) c += (used[k] > 0);
  cnt[threadIdx.x] = c;
  __syncthreads();
  if (threadIdx.x == 0) {
    int tot = 0;
    for (int t = 0; t < 256; ++t) tot += cnt[t];
    out[8388608] = (float)(*lossSum * 0.25 / 8388608.0);
    out[8388609] = (float)tot / 4096.0f;
  }
}

extern "C" void kernel_launch(void* const* d_in, const int* in_sizes, int n_in,
                              void* d_out, int out_size, void* d_ws, size_t ws_size,
                              hipStream_t stream) {
  const float* Z = (const float*)d_in[0];
  const float* E = (const float*)d_in[1];
  float* out = (float*)d_out;
  char* w = (char*)d_ws;

  int* idx = (int*)w;                          // 128 KB
  int* cand = (int*)(w + 131072);              // 128 KB
  float* en1024 = (float*)(w + 262144);        // 16 KB
  int* used = (int*)(w + 278528);              // 16 KB [zeroed]
  double* lossSum = (double*)(w + 294912);     // 8 B   [zeroed]
  int* candCount = (int*)(w + 294920);         // 4 B   [zeroed]
  int* messyCount = (int*)(w + 294924);        // 4 B   [zeroed]

  // d_out doubles as scratch; all consumed before vq_out rewrites out.
  char* Epk16 = (char*)out;                    // 2 MB fp16 image  [0, 524288)
  int* pk0 = (int*)(out + 524288);             // 4 x 32768
  int* pk1 = (int*)(out + 655360);             // 4 x 32768
  int* pk2 = (int*)(out + 786432);             // 4 x 32768
  int* pi0 = (int*)(out + 917504);             // 32768
  int* pi1 = (int*)(out + 950272);             // 32768
  int* pi2 = (int*)(out + 983040);             // 32768
  int* messy = (int*)(out + 1015808);          // 4096
  double* parv = (double*)(out + 1019904);     // 4096 x 16 doubles
  int* parx = (int*)(out + 1150976);           // 4096 x 16 ints

  hipMemsetAsync(w + 278528, 0, 16400, stream);
  vq_prep<<<512, 256, 0, stream>>>(E, (uint4*)Epk16, en1024);
  vq_screen<<<1024, 256, 0, stream>>>(Z, Epk16, en1024, pk0, pk1, pk2);
  vq_merge<<<128, 256, 0, stream>>>(pk0, pk1, pk2, idx, cand, candCount,
                                    messy, messyCount, pi0, pi1, pi2);
  vq_cand3<<<256, 256, 0, stream>>>(Z, E, pi0, pi1, pi2, cand, candCount, idx);
  vq_messy1<<<1024, 256, 0, stream>>>(Z, E, messy, messyCount, parv, parx);
  vq_messy2<<<8, 256, 0, stream>>>(messy, messyCount, parv, parx, idx);
  vq_out<<<1024, 256, 0, stream>>>(Z, E, idx, out, lossSum, used);
  vq_final<<<1, 256, 0, stream>>>(used, lossSum, out);
}